// Round 1
// baseline (413.858 us; speedup 1.0000x reference)
//
#include <hip/hip_runtime.h>

#define NFEAT 128
#define HEADS 8
#define NHID 16
#define SLOPE 0.2f

// ---------------- CSR build ----------------

__global__ void k_init_deg(int* __restrict__ cursor, int n) {
    int i = blockIdx.x * blockDim.x + threadIdx.x;
    if (i < n) cursor[i] = 1;   // self-loop contributes 1 to every node's in-degree
}

__global__ void k_hist(const int* __restrict__ dst, int E, int* __restrict__ cursor) {
    int i = blockIdx.x * blockDim.x + threadIdx.x;
    if (i < E) atomicAdd(&cursor[dst[i]], 1);
}

// single-block exclusive scan of degrees -> row_start[0..n], cursor[i] = row_start[i]
__global__ __launch_bounds__(1024) void k_scan(int* __restrict__ cursor,
                                               int* __restrict__ row_start, int n) {
    __shared__ int sh[1024];
    int t = threadIdx.x;
    int chunk = (n + 1023) >> 10;
    int lo = t * chunk;
    int hi = lo + chunk; if (hi > n) hi = n;
    if (lo > n) lo = n;
    int s = 0;
    for (int i = lo; i < hi; ++i) s += cursor[i];
    sh[t] = s;
    __syncthreads();
    for (int off = 1; off < 1024; off <<= 1) {
        int v = (t >= off) ? sh[t - off] : 0;
        __syncthreads();
        sh[t] += v;
        __syncthreads();
    }
    int run = (t > 0) ? sh[t - 1] : 0;   // exclusive offset for this thread's chunk
    for (int i = lo; i < hi; ++i) {
        int v = cursor[i];
        row_start[i] = run;
        cursor[i] = run;
        run += v;
    }
    if (t == 0) row_start[n] = sh[1023];
}

__global__ void k_scatter(const int* __restrict__ src, const int* __restrict__ dst,
                          int E, int n, int* __restrict__ cursor, int* __restrict__ csr_src) {
    int i = blockIdx.x * blockDim.x + threadIdx.x;
    int total = E + n;
    if (i >= total) return;
    int s, d;
    if (i < E) { s = src[i]; d = dst[i]; }
    else       { s = d = i - E; }          // self loop
    int pos = atomicAdd(&cursor[d], 1);
    csr_src[pos] = s;
}

// ---------------- Layer 1 GEMM: h1 = x @ W1, + attention logits ----------------
// block = 256 threads, 64 nodes per block (8 groups of 8).
// thread t: node lane group (t>>5), 4 consecutive output cols c0=(t&31)*4.

__global__ __launch_bounds__(256) void k_gemm1(const float* __restrict__ x,
                                               const float* __restrict__ W,
                                               const float* __restrict__ a_src,
                                               const float* __restrict__ a_dst,
                                               float* __restrict__ h,
                                               float* __restrict__ als,
                                               float* __restrict__ ald, int n) {
    __shared__ float Wl[128 * 128];   // 64 KB
    __shared__ float xl[8][128];      // 4 KB
    int tid = threadIdx.x;
    for (int i = tid; i < 128 * 128; i += 256) Wl[i] = W[i];
    int base = blockIdx.x * 64;
    int lr = tid >> 5;            // 0..7
    int c0 = (tid & 31) * 4;      // 0,4,...,124
    for (int g = 0; g < 8; ++g) {
        int nb = base + g * 8;
        __syncthreads();
        if (nb + lr < n) {
            *(float4*)&xl[lr][c0] = *(const float4*)&x[(size_t)(nb + lr) * 128 + c0];
        }
        __syncthreads();
        int nn = nb + lr;
        if (nn < n) {
            float4 acc = make_float4(0.f, 0.f, 0.f, 0.f);
#pragma unroll 8
            for (int k = 0; k < 128; ++k) {
                float xv = xl[lr][k];
                float4 w = *(float4*)&Wl[k * 128 + c0];
                acc.x = fmaf(xv, w.x, acc.x);
                acc.y = fmaf(xv, w.y, acc.y);
                acc.z = fmaf(xv, w.z, acc.z);
                acc.w = fmaf(xv, w.w, acc.w);
            }
            *(float4*)&h[(size_t)nn * 128 + c0] = acc;
            float4 as = *(const float4*)&a_src[c0];
            float4 ad = *(const float4*)&a_dst[c0];
            float ps = acc.x * as.x + acc.y * as.y + acc.z * as.z + acc.w * as.w;
            float pd = acc.x * ad.x + acc.y * ad.y + acc.z * ad.z + acc.w * ad.w;
            ps += __shfl_xor(ps, 1); ps += __shfl_xor(ps, 2);
            pd += __shfl_xor(pd, 1); pd += __shfl_xor(pd, 2);
            if ((tid & 3) == 0) {
                int hd = c0 >> 4;
                als[(size_t)nn * 8 + hd] = ps;
                ald[(size_t)nn * 8 + hd] = pd;
            }
        }
    }
}

// ---------------- Layer 1 aggregation: softmax over incoming edges, fused ----------------
// one block (128 threads) per dst node; thread t = channel, head = t>>4

__global__ __launch_bounds__(128) void k_agg1(const float* __restrict__ h,
                                              const float* __restrict__ als,
                                              const float* __restrict__ ald,
                                              const float* __restrict__ bias,
                                              const int* __restrict__ row_start,
                                              const int* __restrict__ csr_src,
                                              float* __restrict__ out, int n) {
    int nn = blockIdx.x;
    int t = threadIdx.x;
    int hd = t >> 4;
    int beg = row_start[nn], end = row_start[nn + 1];
    float aldv = ald[(size_t)nn * 8 + hd];
    float acc = 0.f, denom = 0.f;
    for (int i = beg; i < end; ++i) {
        int s = csr_src[i];
        float e = als[(size_t)s * 8 + hd] + aldv;
        e = (e < 0.f) ? SLOPE * e : e;
        float ex = __expf(e);
        denom += ex;
        acc = fmaf(ex, h[(size_t)s * 128 + t], acc);
    }
    out[(size_t)nn * 128 + t] = fmaxf(acc / denom + bias[t], 0.f);
}

// ---------------- Layer 2 GEMM: h2 = out1 @ W2 (128->16), + logits ----------------
// block = 256 threads, 128 nodes per block (8 groups of 16). thread: node (t>>4), col (t&15)

__global__ __launch_bounds__(256) void k_gemm2(const float* __restrict__ x,
                                               const float* __restrict__ W,
                                               const float* __restrict__ a_src,
                                               const float* __restrict__ a_dst,
                                               float* __restrict__ h,
                                               float* __restrict__ als,
                                               float* __restrict__ ald, int n) {
    __shared__ float Wl[128 * 16];   // 8 KB
    __shared__ float xl[16][128];    // 8 KB
    int tid = threadIdx.x;
    for (int i = tid; i < 128 * 16; i += 256) Wl[i] = W[i];
    int base = blockIdx.x * 128;
    int nl = tid >> 4, c = tid & 15;
    for (int g = 0; g < 8; ++g) {
        int nb = base + g * 16;
        __syncthreads();
        if (nb + nl < n) {
            int kk = c * 8;
            *(float4*)&xl[nl][kk]     = *(const float4*)&x[(size_t)(nb + nl) * 128 + kk];
            *(float4*)&xl[nl][kk + 4] = *(const float4*)&x[(size_t)(nb + nl) * 128 + kk + 4];
        }
        __syncthreads();
        int nn = nb + nl;
        if (nn < n) {
            float acc = 0.f;
#pragma unroll 8
            for (int k = 0; k < 128; ++k)
                acc = fmaf(xl[nl][k], Wl[k * 16 + c], acc);
            h[(size_t)nn * 16 + c] = acc;
            float ps = acc * a_src[c];
            float pd = acc * a_dst[c];
            ps += __shfl_xor(ps, 1); ps += __shfl_xor(ps, 2);
            ps += __shfl_xor(ps, 4); ps += __shfl_xor(ps, 8);
            pd += __shfl_xor(pd, 1); pd += __shfl_xor(pd, 2);
            pd += __shfl_xor(pd, 4); pd += __shfl_xor(pd, 8);
            if (c == 0) { als[nn] = ps; ald[nn] = pd; }
        }
    }
}

// ---------------- Layer 2 aggregation ----------------
// block = 256 threads = 16 nodes x 16 channels

__global__ __launch_bounds__(256) void k_agg2(const float* __restrict__ h,
                                              const float* __restrict__ als,
                                              const float* __restrict__ ald,
                                              const float* __restrict__ bias,
                                              const int* __restrict__ row_start,
                                              const int* __restrict__ csr_src,
                                              float* __restrict__ out, int n) {
    int tid = threadIdx.x;
    int nn = blockIdx.x * 16 + (tid >> 4);
    int c = tid & 15;
    if (nn >= n) return;
    int beg = row_start[nn], end = row_start[nn + 1];
    float aldv = ald[nn];
    float acc = 0.f, denom = 0.f;
    for (int i = beg; i < end; ++i) {
        int s = csr_src[i];
        float e = als[s] + aldv;
        e = (e < 0.f) ? SLOPE * e : e;
        float ex = __expf(e);
        denom += ex;
        acc = fmaf(ex, h[(size_t)s * 16 + c], acc);
    }
    out[(size_t)nn * 16 + c] = fmaxf(acc / denom + bias[c], 0.f);
}

// ---------------- launch ----------------

extern "C" void kernel_launch(void* const* d_in, const int* in_sizes, int n_in,
                              void* d_out, int out_size, void* d_ws, size_t ws_size,
                              hipStream_t stream) {
    const float* x   = (const float*)d_in[0];
    const int*   ei  = (const int*)d_in[1];
    const float* W1  = (const float*)d_in[2];
    const float* as1 = (const float*)d_in[3];
    const float* ad1 = (const float*)d_in[4];
    const float* b1  = (const float*)d_in[5];
    const float* W2  = (const float*)d_in[6];
    const float* as2 = (const float*)d_in[7];
    const float* ad2 = (const float*)d_in[8];
    const float* b2  = (const float*)d_in[9];

    int N = in_sizes[0] / NFEAT;
    int E = in_sizes[1] / 2;
    const int* srcp = ei;
    const int* dstp = ei + E;

    char* ws = (char*)d_ws;
    size_t off = 0;
    auto take = [&](size_t bytes) -> char* {
        char* p = ws + off;
        off = (off + bytes + 255) & ~(size_t)255;
        return p;
    };
    int*   row_start = (int*)take((size_t)(N + 1) * 4);
    int*   cursor    = (int*)take((size_t)N * 4);
    int*   csr       = (int*)take((size_t)(E + N) * 4);
    float* h1        = (float*)take((size_t)N * 128 * 4);
    float* als1      = (float*)take((size_t)N * 8 * 4);
    float* ald1      = (float*)take((size_t)N * 8 * 4);
    float* out1      = (float*)take((size_t)N * 128 * 4);
    float* h2        = (float*)take((size_t)N * 16 * 4);
    float* als2      = (float*)take((size_t)N * 4);
    float* ald2      = (float*)take((size_t)N * 4);

    k_init_deg<<<(N + 255) / 256, 256, 0, stream>>>(cursor, N);
    k_hist<<<(E + 255) / 256, 256, 0, stream>>>(dstp, E, cursor);
    k_scan<<<1, 1024, 0, stream>>>(cursor, row_start, N);
    k_scatter<<<(E + N + 255) / 256, 256, 0, stream>>>(srcp, dstp, E, N, cursor, csr);

    k_gemm1<<<(N + 63) / 64, 256, 0, stream>>>(x, W1, as1, ad1, h1, als1, ald1, N);
    k_agg1<<<N, 128, 0, stream>>>(h1, als1, ald1, b1, row_start, csr, out1, N);
    k_gemm2<<<(N + 127) / 128, 256, 0, stream>>>(out1, W2, as2, ad2, h2, als2, ald2, N);
    k_agg2<<<(N + 15) / 16, 256, 0, stream>>>(h2, als2, ald2, b2, row_start, csr, (float*)d_out, N);
}

// Round 2
// 278.719 us; speedup vs baseline: 1.4849x; 1.4849x over previous
//
#include <hip/hip_runtime.h>

#define NFEAT 128
#define HEADS 8
#define NHID 16
#define SLOPE 0.2f
#define SCAN_TILE 2048   // 256 threads * 8 items

// ---------------- CSR build ----------------

__global__ void k_init_deg(int* __restrict__ cursor, int n) {
    int i = blockIdx.x * blockDim.x + threadIdx.x;
    if (i < n) cursor[i] = 1;   // self-loop contributes 1 to every node's in-degree
}

__global__ void k_hist(const int* __restrict__ dst, int E, int* __restrict__ cursor) {
    int i = blockIdx.x * blockDim.x + threadIdx.x;
    if (i < E) atomicAdd(&cursor[dst[i]], 1);
}

// phase 1: per-block tile sums
__global__ __launch_bounds__(256) void k_scan_part(const int* __restrict__ deg,
                                                   int* __restrict__ part, int n) {
    __shared__ int sh[256];
    int t = threadIdx.x;
    int base = blockIdx.x * SCAN_TILE + t * 8;
    int s = 0;
#pragma unroll
    for (int j = 0; j < 8; ++j) { int i = base + j; if (i < n) s += deg[i]; }
    sh[t] = s;
    __syncthreads();
    for (int off = 128; off > 0; off >>= 1) {
        if (t < off) sh[t] += sh[t + off];
        __syncthreads();
    }
    if (t == 0) part[blockIdx.x] = sh[0];
}

// phase 2: single small block scans the partials (exclusive, in place); writes total
__global__ __launch_bounds__(64) void k_scan_top(int* __restrict__ part, int nb,
                                                 int* __restrict__ row_start, int n) {
    __shared__ int sh[64];
    int t = threadIdx.x;
    int v = (t < nb) ? part[t] : 0;
    sh[t] = v;
    __syncthreads();
    for (int off = 1; off < 64; off <<= 1) {
        int u = (t >= off) ? sh[t - off] : 0;
        __syncthreads();
        sh[t] += u;
        __syncthreads();
    }
    if (t < nb) part[t] = (t > 0) ? sh[t - 1] : 0;
    if (t == 0) row_start[n] = sh[63];
}

// phase 3: per-block exclusive scan + offset -> row_start, cursor
__global__ __launch_bounds__(256) void k_scan_apply(int* __restrict__ deg,
                                                    const int* __restrict__ part,
                                                    int* __restrict__ row_start, int n) {
    __shared__ int sh[256];
    int t = threadIdx.x;
    int base = blockIdx.x * SCAN_TILE + t * 8;
    int v[8];
    int s = 0;
#pragma unroll
    for (int j = 0; j < 8; ++j) { int i = base + j; v[j] = (i < n) ? deg[i] : 0; s += v[j]; }
    sh[t] = s;
    __syncthreads();
    for (int off = 1; off < 256; off <<= 1) {
        int u = (t >= off) ? sh[t - off] : 0;
        __syncthreads();
        sh[t] += u;
        __syncthreads();
    }
    int run = part[blockIdx.x] + ((t > 0) ? sh[t - 1] : 0);
#pragma unroll
    for (int j = 0; j < 8; ++j) {
        int i = base + j;
        if (i < n) { row_start[i] = run; deg[i] = run; run += v[j]; }
    }
}

__global__ void k_scatter(const int* __restrict__ src, const int* __restrict__ dst,
                          int E, int n, int* __restrict__ cursor, int* __restrict__ csr_src) {
    int i = blockIdx.x * blockDim.x + threadIdx.x;
    int total = E + n;
    if (i >= total) return;
    int s, d;
    if (i < E) { s = src[i]; d = dst[i]; }
    else       { s = d = i - E; }          // self loop
    int pos = atomicAdd(&cursor[d], 1);
    csr_src[pos] = s;
}

// ---------------- Layer 1 GEMM: h1 = x @ W1, + attention logits ----------------

__global__ __launch_bounds__(256) void k_gemm1(const float* __restrict__ x,
                                               const float* __restrict__ W,
                                               const float* __restrict__ a_src,
                                               const float* __restrict__ a_dst,
                                               float* __restrict__ h,
                                               float* __restrict__ als,
                                               float* __restrict__ ald, int n) {
    __shared__ float Wl[128 * 128];   // 64 KB
    __shared__ float xl[8][128];      // 4 KB
    int tid = threadIdx.x;
    for (int i = tid; i < 128 * 128; i += 256) Wl[i] = W[i];
    int base = blockIdx.x * 64;
    int lr = tid >> 5;            // 0..7
    int c0 = (tid & 31) * 4;      // 0,4,...,124
    for (int g = 0; g < 8; ++g) {
        int nb = base + g * 8;
        __syncthreads();
        if (nb + lr < n) {
            *(float4*)&xl[lr][c0] = *(const float4*)&x[(size_t)(nb + lr) * 128 + c0];
        }
        __syncthreads();
        int nn = nb + lr;
        if (nn < n) {
            float4 acc = make_float4(0.f, 0.f, 0.f, 0.f);
#pragma unroll 8
            for (int k = 0; k < 128; ++k) {
                float xv = xl[lr][k];
                float4 w = *(float4*)&Wl[k * 128 + c0];
                acc.x = fmaf(xv, w.x, acc.x);
                acc.y = fmaf(xv, w.y, acc.y);
                acc.z = fmaf(xv, w.z, acc.z);
                acc.w = fmaf(xv, w.w, acc.w);
            }
            *(float4*)&h[(size_t)nn * 128 + c0] = acc;
            float4 as = *(const float4*)&a_src[c0];
            float4 ad = *(const float4*)&a_dst[c0];
            float ps = acc.x * as.x + acc.y * as.y + acc.z * as.z + acc.w * as.w;
            float pd = acc.x * ad.x + acc.y * ad.y + acc.z * ad.z + acc.w * ad.w;
            ps += __shfl_xor(ps, 1); ps += __shfl_xor(ps, 2);
            pd += __shfl_xor(pd, 1); pd += __shfl_xor(pd, 2);
            if ((tid & 3) == 0) {
                int hd = c0 >> 4;
                als[(size_t)nn * 8 + hd] = ps;
                ald[(size_t)nn * 8 + hd] = pd;
            }
        }
    }
}

// ---------------- Layer 1 aggregation ----------------
// one block (128 threads) per dst node; thread t = channel, head = t>>4
// 2-way unrolled edge loop for memory-level parallelism.

__global__ __launch_bounds__(128) void k_agg1(const float* __restrict__ h,
                                              const float* __restrict__ als,
                                              const float* __restrict__ ald,
                                              const float* __restrict__ bias,
                                              const int* __restrict__ row_start,
                                              const int* __restrict__ csr_src,
                                              float* __restrict__ out, int n) {
    int nn = blockIdx.x;
    int t = threadIdx.x;
    int hd = t >> 4;
    int beg = row_start[nn], end = row_start[nn + 1];
    float aldv = ald[(size_t)nn * 8 + hd];
    float acc0 = 0.f, acc1 = 0.f, den0 = 0.f, den1 = 0.f;
    int i = beg;
    for (; i + 2 <= end; i += 2) {
        int s0 = csr_src[i];
        int s1 = csr_src[i + 1];
        float a0 = als[(size_t)s0 * 8 + hd];
        float a1 = als[(size_t)s1 * 8 + hd];
        float v0 = h[(size_t)s0 * 128 + t];
        float v1 = h[(size_t)s1 * 128 + t];
        float e0 = a0 + aldv; e0 = (e0 < 0.f) ? SLOPE * e0 : e0;
        float e1 = a1 + aldv; e1 = (e1 < 0.f) ? SLOPE * e1 : e1;
        float x0 = __expf(e0);
        float x1 = __expf(e1);
        den0 += x0; den1 += x1;
        acc0 = fmaf(x0, v0, acc0);
        acc1 = fmaf(x1, v1, acc1);
    }
    if (i < end) {
        int s0 = csr_src[i];
        float e0 = als[(size_t)s0 * 8 + hd] + aldv;
        e0 = (e0 < 0.f) ? SLOPE * e0 : e0;
        float x0 = __expf(e0);
        den0 += x0;
        acc0 = fmaf(x0, h[(size_t)s0 * 128 + t], acc0);
    }
    out[(size_t)nn * 128 + t] = fmaxf((acc0 + acc1) / (den0 + den1) + bias[t], 0.f);
}

// ---------------- Layer 2 GEMM: h2 = out1 @ W2 (128->16), + logits ----------------

__global__ __launch_bounds__(256) void k_gemm2(const float* __restrict__ x,
                                               const float* __restrict__ W,
                                               const float* __restrict__ a_src,
                                               const float* __restrict__ a_dst,
                                               float* __restrict__ h,
                                               float* __restrict__ als,
                                               float* __restrict__ ald, int n) {
    __shared__ float Wl[128 * 16];   // 8 KB
    __shared__ float xl[16][128];    // 8 KB
    int tid = threadIdx.x;
    for (int i = tid; i < 128 * 16; i += 256) Wl[i] = W[i];
    int base = blockIdx.x * 128;
    int nl = tid >> 4, c = tid & 15;
    for (int g = 0; g < 8; ++g) {
        int nb = base + g * 16;
        __syncthreads();
        if (nb + nl < n) {
            int kk = c * 8;
            *(float4*)&xl[nl][kk]     = *(const float4*)&x[(size_t)(nb + nl) * 128 + kk];
            *(float4*)&xl[nl][kk + 4] = *(const float4*)&x[(size_t)(nb + nl) * 128 + kk + 4];
        }
        __syncthreads();
        int nn = nb + nl;
        if (nn < n) {
            float acc = 0.f;
#pragma unroll 8
            for (int k = 0; k < 128; ++k)
                acc = fmaf(xl[nl][k], Wl[k * 16 + c], acc);
            h[(size_t)nn * 16 + c] = acc;
            float ps = acc * a_src[c];
            float pd = acc * a_dst[c];
            ps += __shfl_xor(ps, 1); ps += __shfl_xor(ps, 2);
            ps += __shfl_xor(ps, 4); ps += __shfl_xor(ps, 8);
            pd += __shfl_xor(pd, 1); pd += __shfl_xor(pd, 2);
            pd += __shfl_xor(pd, 4); pd += __shfl_xor(pd, 8);
            if (c == 0) { als[nn] = ps; ald[nn] = pd; }
        }
    }
}

// ---------------- Layer 2 aggregation ----------------

__global__ __launch_bounds__(256) void k_agg2(const float* __restrict__ h,
                                              const float* __restrict__ als,
                                              const float* __restrict__ ald,
                                              const float* __restrict__ bias,
                                              const int* __restrict__ row_start,
                                              const int* __restrict__ csr_src,
                                              float* __restrict__ out, int n) {
    int tid = threadIdx.x;
    int nn = blockIdx.x * 16 + (tid >> 4);
    int c = tid & 15;
    if (nn >= n) return;
    int beg = row_start[nn], end = row_start[nn + 1];
    float aldv = ald[nn];
    float acc0 = 0.f, acc1 = 0.f, den0 = 0.f, den1 = 0.f;
    int i = beg;
    for (; i + 2 <= end; i += 2) {
        int s0 = csr_src[i];
        int s1 = csr_src[i + 1];
        float a0 = als[s0];
        float a1 = als[s1];
        float v0 = h[(size_t)s0 * 16 + c];
        float v1 = h[(size_t)s1 * 16 + c];
        float e0 = a0 + aldv; e0 = (e0 < 0.f) ? SLOPE * e0 : e0;
        float e1 = a1 + aldv; e1 = (e1 < 0.f) ? SLOPE * e1 : e1;
        float x0 = __expf(e0);
        float x1 = __expf(e1);
        den0 += x0; den1 += x1;
        acc0 = fmaf(x0, v0, acc0);
        acc1 = fmaf(x1, v1, acc1);
    }
    if (i < end) {
        int s0 = csr_src[i];
        float e0 = als[s0] + aldv;
        e0 = (e0 < 0.f) ? SLOPE * e0 : e0;
        float x0 = __expf(e0);
        den0 += x0;
        acc0 = fmaf(x0, h[(size_t)s0 * 16 + c], acc0);
    }
    out[(size_t)nn * 16 + c] = fmaxf((acc0 + acc1) / (den0 + den1) + bias[c], 0.f);
}

// ---------------- launch ----------------

extern "C" void kernel_launch(void* const* d_in, const int* in_sizes, int n_in,
                              void* d_out, int out_size, void* d_ws, size_t ws_size,
                              hipStream_t stream) {
    const float* x   = (const float*)d_in[0];
    const int*   ei  = (const int*)d_in[1];
    const float* W1  = (const float*)d_in[2];
    const float* as1 = (const float*)d_in[3];
    const float* ad1 = (const float*)d_in[4];
    const float* b1  = (const float*)d_in[5];
    const float* W2  = (const float*)d_in[6];
    const float* as2 = (const float*)d_in[7];
    const float* ad2 = (const float*)d_in[8];
    const float* b2  = (const float*)d_in[9];

    int N = in_sizes[0] / NFEAT;
    int E = in_sizes[1] / 2;
    const int* srcp = ei;
    const int* dstp = ei + E;
    int nb_scan = (N + SCAN_TILE - 1) / SCAN_TILE;

    char* ws = (char*)d_ws;
    size_t off = 0;
    auto take = [&](size_t bytes) -> char* {
        char* p = ws + off;
        off = (off + bytes + 255) & ~(size_t)255;
        return p;
    };
    int*   row_start = (int*)take((size_t)(N + 1) * 4);
    int*   cursor    = (int*)take((size_t)N * 4);
    int*   part      = (int*)take((size_t)nb_scan * 4);
    int*   csr       = (int*)take((size_t)(E + N) * 4);
    float* h1        = (float*)take((size_t)N * 128 * 4);
    float* als1      = (float*)take((size_t)N * 8 * 4);
    float* ald1      = (float*)take((size_t)N * 8 * 4);
    float* out1      = (float*)take((size_t)N * 128 * 4);
    float* h2        = (float*)take((size_t)N * 16 * 4);
    float* als2      = (float*)take((size_t)N * 4);
    float* ald2      = (float*)take((size_t)N * 4);

    k_init_deg<<<(N + 255) / 256, 256, 0, stream>>>(cursor, N);
    k_hist<<<(E + 255) / 256, 256, 0, stream>>>(dstp, E, cursor);
    k_scan_part<<<nb_scan, 256, 0, stream>>>(cursor, part, N);
    k_scan_top<<<1, 64, 0, stream>>>(part, nb_scan, row_start, N);
    k_scan_apply<<<nb_scan, 256, 0, stream>>>(cursor, part, row_start, N);
    k_scatter<<<(E + N + 255) / 256, 256, 0, stream>>>(srcp, dstp, E, N, cursor, csr);

    k_gemm1<<<(N + 63) / 64, 256, 0, stream>>>(x, W1, as1, ad1, h1, als1, ald1, N);
    k_agg1<<<N, 128, 0, stream>>>(h1, als1, ald1, b1, row_start, csr, out1, N);
    k_gemm2<<<(N + 127) / 128, 256, 0, stream>>>(out1, W2, as2, ad2, h2, als2, ald2, N);
    k_agg2<<<(N + 15) / 16, 256, 0, stream>>>(h2, als2, ald2, b2, row_start, csr, (float*)d_out, N);
}

// Round 3
// 272.904 us; speedup vs baseline: 1.5165x; 1.0213x over previous
//
#include <hip/hip_runtime.h>

#define NFEAT 128
#define HEADS 8
#define NHID 16
#define SLOPE 0.2f
#define SCAN_TILE 2048   // 256 threads * 8 items

// bf16 round-to-nearest-even pack helpers
__device__ __forceinline__ unsigned bf16rne(float f) {
    unsigned u = __float_as_uint(f);
    return (u + 0x7FFFu + ((u >> 16) & 1u)) >> 16;
}
__device__ __forceinline__ unsigned pack2bf16(float a, float b) {
    return bf16rne(a) | (bf16rne(b) << 16);
}

// ---------------- CSR build ----------------

__global__ void k_init_deg(int* __restrict__ cursor, int n) {
    int i = blockIdx.x * blockDim.x + threadIdx.x;
    if (i < n) cursor[i] = 1;   // self-loop contributes 1 to every node's in-degree
}

__global__ void k_hist(const int* __restrict__ dst, int E, int* __restrict__ cursor) {
    int i = blockIdx.x * blockDim.x + threadIdx.x;
    if (i < E) atomicAdd(&cursor[dst[i]], 1);
}

// phase 1: per-block tile sums
__global__ __launch_bounds__(256) void k_scan_part(const int* __restrict__ deg,
                                                   int* __restrict__ part, int n) {
    __shared__ int sh[256];
    int t = threadIdx.x;
    int base = blockIdx.x * SCAN_TILE + t * 8;
    int s = 0;
#pragma unroll
    for (int j = 0; j < 8; ++j) { int i = base + j; if (i < n) s += deg[i]; }
    sh[t] = s;
    __syncthreads();
    for (int off = 128; off > 0; off >>= 1) {
        if (t < off) sh[t] += sh[t + off];
        __syncthreads();
    }
    if (t == 0) part[blockIdx.x] = sh[0];
}

// phase 2: single small block scans the partials (exclusive, in place); writes total
__global__ __launch_bounds__(64) void k_scan_top(int* __restrict__ part, int nb,
                                                 int* __restrict__ row_start, int n) {
    __shared__ int sh[64];
    int t = threadIdx.x;
    int v = (t < nb) ? part[t] : 0;
    sh[t] = v;
    __syncthreads();
    for (int off = 1; off < 64; off <<= 1) {
        int u = (t >= off) ? sh[t - off] : 0;
        __syncthreads();
        sh[t] += u;
        __syncthreads();
    }
    if (t < nb) part[t] = (t > 0) ? sh[t - 1] : 0;
    if (t == 0) row_start[n] = sh[63];
}

// phase 3: per-block exclusive scan + offset -> row_start, cursor
__global__ __launch_bounds__(256) void k_scan_apply(int* __restrict__ deg,
                                                    const int* __restrict__ part,
                                                    int* __restrict__ row_start, int n) {
    __shared__ int sh[256];
    int t = threadIdx.x;
    int base = blockIdx.x * SCAN_TILE + t * 8;
    int v[8];
    int s = 0;
#pragma unroll
    for (int j = 0; j < 8; ++j) { int i = base + j; v[j] = (i < n) ? deg[i] : 0; s += v[j]; }
    sh[t] = s;
    __syncthreads();
    for (int off = 1; off < 256; off <<= 1) {
        int u = (t >= off) ? sh[t - off] : 0;
        __syncthreads();
        sh[t] += u;
        __syncthreads();
    }
    int run = part[blockIdx.x] + ((t > 0) ? sh[t - 1] : 0);
#pragma unroll
    for (int j = 0; j < 8; ++j) {
        int i = base + j;
        if (i < n) { row_start[i] = run; deg[i] = run; run += v[j]; }
    }
}

__global__ void k_scatter(const int* __restrict__ src, const int* __restrict__ dst,
                          int E, int n, int* __restrict__ cursor, int* __restrict__ csr_src) {
    int i = blockIdx.x * blockDim.x + threadIdx.x;
    int total = E + n;
    if (i >= total) return;
    int s, d;
    if (i < E) { s = src[i]; d = dst[i]; }
    else       { s = d = i - E; }          // self loop
    int pos = atomicAdd(&cursor[d], 1);
    csr_src[pos] = s;
}

// ---------------- Layer 1 GEMM: h1(bf16) = x @ W1, + attention logits (f32) ----------------

__global__ __launch_bounds__(256) void k_gemm1(const float* __restrict__ x,
                                               const float* __restrict__ W,
                                               const float* __restrict__ a_src,
                                               const float* __restrict__ a_dst,
                                               unsigned short* __restrict__ h,   // bf16 [n][128]
                                               float* __restrict__ als,
                                               float* __restrict__ ald, int n) {
    __shared__ float Wl[128 * 128];   // 64 KB
    __shared__ float xl[8][128];      // 4 KB
    int tid = threadIdx.x;
    for (int i = tid; i < 128 * 128; i += 256) Wl[i] = W[i];
    int base = blockIdx.x * 64;
    int lr = tid >> 5;            // 0..7
    int c0 = (tid & 31) * 4;      // 0,4,...,124
    for (int g = 0; g < 8; ++g) {
        int nb = base + g * 8;
        __syncthreads();
        if (nb + lr < n) {
            *(float4*)&xl[lr][c0] = *(const float4*)&x[(size_t)(nb + lr) * 128 + c0];
        }
        __syncthreads();
        int nn = nb + lr;
        if (nn < n) {
            float4 acc = make_float4(0.f, 0.f, 0.f, 0.f);
#pragma unroll 8
            for (int k = 0; k < 128; ++k) {
                float xv = xl[lr][k];
                float4 w = *(float4*)&Wl[k * 128 + c0];
                acc.x = fmaf(xv, w.x, acc.x);
                acc.y = fmaf(xv, w.y, acc.y);
                acc.z = fmaf(xv, w.z, acc.z);
                acc.w = fmaf(xv, w.w, acc.w);
            }
            uint2 packed;
            packed.x = pack2bf16(acc.x, acc.y);
            packed.y = pack2bf16(acc.z, acc.w);
            *(uint2*)&h[(size_t)nn * 128 + c0] = packed;
            float4 as = *(const float4*)&a_src[c0];
            float4 ad = *(const float4*)&a_dst[c0];
            float ps = acc.x * as.x + acc.y * as.y + acc.z * as.z + acc.w * as.w;
            float pd = acc.x * ad.x + acc.y * ad.y + acc.z * ad.z + acc.w * ad.w;
            ps += __shfl_xor(ps, 1); ps += __shfl_xor(ps, 2);
            pd += __shfl_xor(pd, 1); pd += __shfl_xor(pd, 2);
            if ((tid & 3) == 0) {
                int hd = c0 >> 4;
                als[(size_t)nn * 8 + hd] = ps;
                ald[(size_t)nn * 8 + hd] = pd;
            }
        }
    }
}

// ---------------- Layer 1 aggregation ----------------
// block = 128 threads = 2 nodes x 64 lanes; lane l handles channels 2l, 2l+1 (one bf16x2 word)

__global__ __launch_bounds__(128) void k_agg1(const unsigned short* __restrict__ h,
                                              const float* __restrict__ als,
                                              const float* __restrict__ ald,
                                              const float* __restrict__ bias,
                                              const int* __restrict__ row_start,
                                              const int* __restrict__ csr_src,
                                              float* __restrict__ out, int n) {
    int t = threadIdx.x;
    int l = t & 63;
    int nn = blockIdx.x * 2 + (t >> 6);
    if (nn >= n) return;
    int hd = l >> 3;                       // head of channel 2l (== head of 2l+1)
    const unsigned* hu = (const unsigned*)h;   // bf16x2 words, [n][64]
    int beg = row_start[nn], end = row_start[nn + 1];
    float aldv = ald[(size_t)nn * 8 + hd];
    float aX0 = 0.f, aY0 = 0.f, aX1 = 0.f, aY1 = 0.f, den0 = 0.f, den1 = 0.f;
    int i = beg;
    for (; i + 2 <= end; i += 2) {
        int s0 = csr_src[i];
        int s1 = csr_src[i + 1];
        float e0 = als[(size_t)s0 * 8 + hd];
        float e1 = als[(size_t)s1 * 8 + hd];
        unsigned v0 = hu[(size_t)s0 * 64 + l];
        unsigned v1 = hu[(size_t)s1 * 64 + l];
        e0 += aldv; e0 = (e0 < 0.f) ? SLOPE * e0 : e0;
        e1 += aldv; e1 = (e1 < 0.f) ? SLOPE * e1 : e1;
        float x0 = __expf(e0);
        float x1 = __expf(e1);
        den0 += x0; den1 += x1;
        aX0 = fmaf(x0, __uint_as_float(v0 << 16), aX0);
        aY0 = fmaf(x0, __uint_as_float(v0 & 0xFFFF0000u), aY0);
        aX1 = fmaf(x1, __uint_as_float(v1 << 16), aX1);
        aY1 = fmaf(x1, __uint_as_float(v1 & 0xFFFF0000u), aY1);
    }
    if (i < end) {
        int s0 = csr_src[i];
        float e0 = als[(size_t)s0 * 8 + hd] + aldv;
        unsigned v0 = hu[(size_t)s0 * 64 + l];
        e0 = (e0 < 0.f) ? SLOPE * e0 : e0;
        float x0 = __expf(e0);
        den0 += x0;
        aX0 = fmaf(x0, __uint_as_float(v0 << 16), aX0);
        aY0 = fmaf(x0, __uint_as_float(v0 & 0xFFFF0000u), aY0);
    }
    float inv = 1.f / (den0 + den1);
    float2 bv = *(const float2*)&bias[2 * l];
    float2 res;
    res.x = fmaxf((aX0 + aX1) * inv + bv.x, 0.f);
    res.y = fmaxf((aY0 + aY1) * inv + bv.y, 0.f);
    *(float2*)&out[(size_t)nn * 128 + 2 * l] = res;
}

// ---------------- Layer 2 GEMM: h2 = out1 @ W2 (128->16), + logits ----------------

__global__ __launch_bounds__(256) void k_gemm2(const float* __restrict__ x,
                                               const float* __restrict__ W,
                                               const float* __restrict__ a_src,
                                               const float* __restrict__ a_dst,
                                               float* __restrict__ h,
                                               float* __restrict__ als,
                                               float* __restrict__ ald, int n) {
    __shared__ float Wl[128 * 16];   // 8 KB
    __shared__ float xl[16][128];    // 8 KB
    int tid = threadIdx.x;
    for (int i = tid; i < 128 * 16; i += 256) Wl[i] = W[i];
    int base = blockIdx.x * 128;
    int nl = tid >> 4, c = tid & 15;
    for (int g = 0; g < 8; ++g) {
        int nb = base + g * 16;
        __syncthreads();
        if (nb + nl < n) {
            int kk = c * 8;
            *(float4*)&xl[nl][kk]     = *(const float4*)&x[(size_t)(nb + nl) * 128 + kk];
            *(float4*)&xl[nl][kk + 4] = *(const float4*)&x[(size_t)(nb + nl) * 128 + kk + 4];
        }
        __syncthreads();
        int nn = nb + nl;
        if (nn < n) {
            float acc = 0.f;
#pragma unroll 8
            for (int k = 0; k < 128; ++k)
                acc = fmaf(xl[nl][k], Wl[k * 16 + c], acc);
            h[(size_t)nn * 16 + c] = acc;
            float ps = acc * a_src[c];
            float pd = acc * a_dst[c];
            ps += __shfl_xor(ps, 1); ps += __shfl_xor(ps, 2);
            ps += __shfl_xor(ps, 4); ps += __shfl_xor(ps, 8);
            pd += __shfl_xor(pd, 1); pd += __shfl_xor(pd, 2);
            pd += __shfl_xor(pd, 4); pd += __shfl_xor(pd, 8);
            if (c == 0) { als[nn] = ps; ald[nn] = pd; }
        }
    }
}

// ---------------- Layer 2 aggregation ----------------

__global__ __launch_bounds__(256) void k_agg2(const float* __restrict__ h,
                                              const float* __restrict__ als,
                                              const float* __restrict__ ald,
                                              const float* __restrict__ bias,
                                              const int* __restrict__ row_start,
                                              const int* __restrict__ csr_src,
                                              float* __restrict__ out, int n) {
    int tid = threadIdx.x;
    int nn = blockIdx.x * 16 + (tid >> 4);
    int c = tid & 15;
    if (nn >= n) return;
    int beg = row_start[nn], end = row_start[nn + 1];
    float aldv = ald[nn];
    float acc0 = 0.f, acc1 = 0.f, den0 = 0.f, den1 = 0.f;
    int i = beg;
    for (; i + 2 <= end; i += 2) {
        int s0 = csr_src[i];
        int s1 = csr_src[i + 1];
        float a0 = als[s0];
        float a1 = als[s1];
        float v0 = h[(size_t)s0 * 16 + c];
        float v1 = h[(size_t)s1 * 16 + c];
        float e0 = a0 + aldv; e0 = (e0 < 0.f) ? SLOPE * e0 : e0;
        float e1 = a1 + aldv; e1 = (e1 < 0.f) ? SLOPE * e1 : e1;
        float x0 = __expf(e0);
        float x1 = __expf(e1);
        den0 += x0; den1 += x1;
        acc0 = fmaf(x0, v0, acc0);
        acc1 = fmaf(x1, v1, acc1);
    }
    if (i < end) {
        int s0 = csr_src[i];
        float e0 = als[s0] + aldv;
        e0 = (e0 < 0.f) ? SLOPE * e0 : e0;
        float x0 = __expf(e0);
        den0 += x0;
        acc0 = fmaf(x0, h[(size_t)s0 * 16 + c], acc0);
    }
    out[(size_t)nn * 16 + c] = fmaxf((acc0 + acc1) / (den0 + den1) + bias[c], 0.f);
}

// ---------------- launch ----------------

extern "C" void kernel_launch(void* const* d_in, const int* in_sizes, int n_in,
                              void* d_out, int out_size, void* d_ws, size_t ws_size,
                              hipStream_t stream) {
    const float* x   = (const float*)d_in[0];
    const int*   ei  = (const int*)d_in[1];
    const float* W1  = (const float*)d_in[2];
    const float* as1 = (const float*)d_in[3];
    const float* ad1 = (const float*)d_in[4];
    const float* b1  = (const float*)d_in[5];
    const float* W2  = (const float*)d_in[6];
    const float* as2 = (const float*)d_in[7];
    const float* ad2 = (const float*)d_in[8];
    const float* b2  = (const float*)d_in[9];

    int N = in_sizes[0] / NFEAT;
    int E = in_sizes[1] / 2;
    const int* srcp = ei;
    const int* dstp = ei + E;
    int nb_scan = (N + SCAN_TILE - 1) / SCAN_TILE;

    char* ws = (char*)d_ws;
    size_t off = 0;
    auto take = [&](size_t bytes) -> char* {
        char* p = ws + off;
        off = (off + bytes + 255) & ~(size_t)255;
        return p;
    };
    int*            row_start = (int*)take((size_t)(N + 1) * 4);
    int*            cursor    = (int*)take((size_t)N * 4);
    int*            part      = (int*)take((size_t)nb_scan * 4);
    int*            csr       = (int*)take((size_t)(E + N) * 4);
    unsigned short* h1        = (unsigned short*)take((size_t)N * 128 * 2);  // bf16
    float*          als1      = (float*)take((size_t)N * 8 * 4);
    float*          ald1      = (float*)take((size_t)N * 8 * 4);
    float*          out1      = (float*)take((size_t)N * 128 * 4);
    float*          h2        = (float*)take((size_t)N * 16 * 4);
    float*          als2      = (float*)take((size_t)N * 4);
    float*          ald2      = (float*)take((size_t)N * 4);

    k_init_deg<<<(N + 255) / 256, 256, 0, stream>>>(cursor, N);
    k_hist<<<(E + 255) / 256, 256, 0, stream>>>(dstp, E, cursor);
    k_scan_part<<<nb_scan, 256, 0, stream>>>(cursor, part, N);
    k_scan_top<<<1, 64, 0, stream>>>(part, nb_scan, row_start, N);
    k_scan_apply<<<nb_scan, 256, 0, stream>>>(cursor, part, row_start, N);
    k_scatter<<<(E + N + 255) / 256, 256, 0, stream>>>(srcp, dstp, E, N, cursor, csr);

    k_gemm1<<<(N + 63) / 64, 256, 0, stream>>>(x, W1, as1, ad1, h1, als1, ald1, N);
    k_agg1<<<(N + 1) / 2, 128, 0, stream>>>(h1, als1, ald1, b1, row_start, csr, out1, N);
    k_gemm2<<<(N + 127) / 128, 256, 0, stream>>>(out1, W2, as2, ad2, h2, als2, ald2, N);
    k_agg2<<<(N + 15) / 16, 256, 0, stream>>>(h2, als2, ald2, b2, row_start, csr, (float*)d_out, N);
}

// Round 4
// 245.187 us; speedup vs baseline: 1.6879x; 1.1130x over previous
//
#include <hip/hip_runtime.h>

#define NFEAT 128
#define HEADS 8
#define NHID 16
#define SLOPE 0.2f
#define SCAN_TILE 2048   // 256 threads * 8 items

typedef short s8v __attribute__((ext_vector_type(8)));   // 8 bf16 (4 VGPRs) MFMA A/B frag
typedef float f4v __attribute__((ext_vector_type(4)));   // 4 f32 MFMA C/D frag

// bf16 round-to-nearest-even pack helpers
__device__ __forceinline__ unsigned bf16rne(float f) {
    unsigned u = __float_as_uint(f);
    return (u + 0x7FFFu + ((u >> 16) & 1u)) >> 16;
}
__device__ __forceinline__ unsigned pack2bf16(float a, float b) {
    return bf16rne(a) | (bf16rne(b) << 16);
}

// ---------------- CSR build ----------------

__global__ void k_init_deg(int* __restrict__ cursor, int n) {
    int i = blockIdx.x * blockDim.x + threadIdx.x;
    if (i < n) cursor[i] = 1;   // self-loop contributes 1 to every node's in-degree
}

__global__ void k_hist(const int* __restrict__ dst, int E, int* __restrict__ cursor) {
    int i = blockIdx.x * blockDim.x + threadIdx.x;
    if (i < E) atomicAdd(&cursor[dst[i]], 1);
}

// phase 1: per-block tile sums
__global__ __launch_bounds__(256) void k_scan_part(const int* __restrict__ deg,
                                                   int* __restrict__ part, int n) {
    __shared__ int sh[256];
    int t = threadIdx.x;
    int base = blockIdx.x * SCAN_TILE + t * 8;
    int s = 0;
#pragma unroll
    for (int j = 0; j < 8; ++j) { int i = base + j; if (i < n) s += deg[i]; }
    sh[t] = s;
    __syncthreads();
    for (int off = 128; off > 0; off >>= 1) {
        if (t < off) sh[t] += sh[t + off];
        __syncthreads();
    }
    if (t == 0) part[blockIdx.x] = sh[0];
}

// phase 2: single small block scans the partials (exclusive, in place); writes total
__global__ __launch_bounds__(64) void k_scan_top(int* __restrict__ part, int nb,
                                                 int* __restrict__ row_start, int n) {
    __shared__ int sh[64];
    int t = threadIdx.x;
    int v = (t < nb) ? part[t] : 0;
    sh[t] = v;
    __syncthreads();
    for (int off = 1; off < 64; off <<= 1) {
        int u = (t >= off) ? sh[t - off] : 0;
        __syncthreads();
        sh[t] += u;
        __syncthreads();
    }
    if (t < nb) part[t] = (t > 0) ? sh[t - 1] : 0;
    if (t == 0) row_start[n] = sh[63];
}

// phase 3: per-block exclusive scan + offset -> row_start, cursor
__global__ __launch_bounds__(256) void k_scan_apply(int* __restrict__ deg,
                                                    const int* __restrict__ part,
                                                    int* __restrict__ row_start, int n) {
    __shared__ int sh[256];
    int t = threadIdx.x;
    int base = blockIdx.x * SCAN_TILE + t * 8;
    int v[8];
    int s = 0;
#pragma unroll
    for (int j = 0; j < 8; ++j) { int i = base + j; v[j] = (i < n) ? deg[i] : 0; s += v[j]; }
    sh[t] = s;
    __syncthreads();
    for (int off = 1; off < 256; off <<= 1) {
        int u = (t >= off) ? sh[t - off] : 0;
        __syncthreads();
        sh[t] += u;
        __syncthreads();
    }
    int run = part[blockIdx.x] + ((t > 0) ? sh[t - 1] : 0);
#pragma unroll
    for (int j = 0; j < 8; ++j) {
        int i = base + j;
        if (i < n) { row_start[i] = run; deg[i] = run; run += v[j]; }
    }
}

__global__ void k_scatter(const int* __restrict__ src, const int* __restrict__ dst,
                          int E, int n, int* __restrict__ cursor, int* __restrict__ csr_src) {
    int i = blockIdx.x * blockDim.x + threadIdx.x;
    int total = E + n;
    if (i >= total) return;
    int s, d;
    if (i < E) { s = src[i]; d = dst[i]; }
    else       { s = d = i - E; }          // self loop
    int pos = atomicAdd(&cursor[d], 1);
    csr_src[pos] = s;
}

// ---------------- x -> bf16 cast ----------------

__global__ __launch_bounds__(256) void k_cast_x(const float* __restrict__ x,
                                                unsigned* __restrict__ xb, int n8) {
    int i = blockIdx.x * 256 + threadIdx.x;   // 8 floats per thread
    if (i >= n8) return;
    const float4* xp = (const float4*)x;
    float4 v0 = xp[(size_t)i * 2];
    float4 v1 = xp[(size_t)i * 2 + 1];
    uint4 o;
    o.x = pack2bf16(v0.x, v0.y); o.y = pack2bf16(v0.z, v0.w);
    o.z = pack2bf16(v1.x, v1.y); o.w = pack2bf16(v1.z, v1.w);
    ((uint4*)xb)[i] = o;
}

// ---------------- W1 transpose (Wt[col][k] bf16) + Aat ([16 j][128 k] bf16) ----------------
// Aat rows 0..7 = a_src spread block-diagonally (col j gets a_src[k] iff k>>4==j),
// rows 8..15 same for a_dst. Then [als|ald] = h @ Aat^T via one MFMA chain.

__global__ __launch_bounds__(256) void k_prep(const float* __restrict__ W,
                                              const float* __restrict__ a_src,
                                              const float* __restrict__ a_dst,
                                              unsigned* __restrict__ Wt_u32,        // [128][64]
                                              unsigned short* __restrict__ Aat) {   // [16][128]
    int t = threadIdx.x;
    int c = t & 127, half = t >> 7;
    unsigned prev = 0;
    for (int i = 0; i < 64; ++i) {
        int k = half * 64 + i;
        unsigned b = bf16rne(W[k * 128 + c]);
        if (i & 1) Wt_u32[c * 64 + half * 32 + (i >> 1)] = prev | (b << 16);
        else prev = b;
    }
    for (int idx = t * 8; idx < t * 8 + 8; ++idx) {
        int j = idx >> 7, k = idx & 127;
        float v = 0.f;
        if (j < 8)  { if ((k >> 4) == j)     v = a_src[k]; }
        else        { if ((k >> 4) == j - 8) v = a_dst[k]; }
        Aat[idx] = (unsigned short)bf16rne(v);
    }
}

// ---------------- Layer 1 GEMM via MFMA: h1(bf16) = x @ W1, logits via 2nd MFMA ----------------
// 256 threads = 4 waves; wave handles 32 nodes (2 A-tiles of 16), all 128 cols (8 col-tiles).
// A-frag: lane l holds A[row=l&15][k=8*(l>>4)+i]; B-frag: B[k=8*(l>>4)+i][col=l&15];
// C/D:    lane l holds D[row=4*(l>>4)+j][col=l&15]  (m89-verified layout).

__global__ __launch_bounds__(256) void k_gemm1m(const unsigned short* __restrict__ xb,
                                                const unsigned short* __restrict__ Wt,
                                                const unsigned short* __restrict__ Aat,
                                                unsigned* __restrict__ h1u,     // [n][64] bf16x2
                                                float* __restrict__ als,
                                                float* __restrict__ ald, int n) {
    __shared__ unsigned hl[4][32 * 64];   // per-wave h repack (swizzled), 32 KB
    int tid = threadIdx.x;
    int w = tid >> 6, l = tid & 63;
    int l15 = l & 15, lq = l >> 4;
    int wbase = blockIdx.x * 128 + w * 32;
    f4v acc[2][8] = {};
    int r0 = min(wbase + l15, n - 1);
    int r1 = min(wbase + 16 + l15, n - 1);
#pragma unroll
    for (int kb = 0; kb < 4; ++kb) {
        int ko = kb * 32 + lq * 8;
        s8v a0 = *(const s8v*)&xb[(size_t)r0 * 128 + ko];
        s8v a1 = *(const s8v*)&xb[(size_t)r1 * 128 + ko];
#pragma unroll
        for (int cg = 0; cg < 8; ++cg) {
            s8v b = *(const s8v*)&Wt[(size_t)(cg * 16 + l15) * 128 + ko];
            acc[0][cg] = __builtin_amdgcn_mfma_f32_16x16x32_bf16(a0, b, acc[0][cg], 0, 0, 0);
            acc[1][cg] = __builtin_amdgcn_mfma_f32_16x16x32_bf16(a1, b, acc[1][cg], 0, 0, 0);
        }
    }
    // pack h to bf16 pairs -> swizzled LDS (granule16 g' = g ^ (node&15))
    unsigned* myl = hl[w];
#pragma unroll
    for (int T = 0; T < 2; ++T) {
#pragma unroll
        for (int cg = 0; cg < 8; ++cg) {
#pragma unroll
            for (int j = 0; j < 4; ++j) {
                float v = acc[T][cg][j];
                float vo = __shfl_xor(v, 1);
                if ((l15 & 1) == 0) {
                    int nd = T * 16 + lq * 4 + j;
                    int wd = cg * 8 + (l15 >> 1);
                    int widx = nd * 64 + (((wd >> 2) ^ (nd & 15)) << 2) + (wd & 3);
                    myl[widx] = pack2bf16(v, vo);
                }
            }
        }
    }
    __syncthreads();
    // coalesced h1 store: quarter-wave covers one node's 256 B
#pragma unroll
    for (int it = 0; it < 8; ++it) {
        int nd = it * 4 + lq;
        int node = wbase + nd;
        uint4 vv = *(const uint4*)&myl[nd * 64 + ((l15 ^ (nd & 15)) << 2)];
        if (node < n) *(uint4*)&h1u[(size_t)node * 64 + l15 * 4] = vv;
    }
    // attention logits: D2 = h_tile @ Aat^T  (16x16, K=128)
#pragma unroll
    for (int T = 0; T < 2; ++T) {
        f4v acca = {};
#pragma unroll
        for (int kb = 0; kb < 4; ++kb) {
            int nd = T * 16 + l15;
            s8v ah = *(const s8v*)&myl[nd * 64 + (((kb * 4 + lq) ^ (nd & 15)) << 2)];
            s8v bb = *(const s8v*)&Aat[l15 * 128 + kb * 32 + lq * 8];
            acca = __builtin_amdgcn_mfma_f32_16x16x32_bf16(ah, bb, acca, 0, 0, 0);
        }
#pragma unroll
        for (int j = 0; j < 4; ++j) {
            int node = wbase + T * 16 + lq * 4 + j;
            if (node < n) {
                if (l15 < 8) als[(size_t)node * 8 + l15] = acca[j];
                else         ald[(size_t)node * 8 + (l15 - 8)] = acca[j];
            }
        }
    }
}

// ---------------- Layer 1 aggregation ----------------
// block = 128 threads = 2 nodes x 64 lanes; lane l handles channels 2l, 2l+1 (one bf16x2 word)

__global__ __launch_bounds__(128) void k_agg1(const unsigned* __restrict__ hu,
                                              const float* __restrict__ als,
                                              const float* __restrict__ ald,
                                              const float* __restrict__ bias,
                                              const int* __restrict__ row_start,
                                              const int* __restrict__ csr_src,
                                              float* __restrict__ out, int n) {
    int t = threadIdx.x;
    int l = t & 63;
    int nn = blockIdx.x * 2 + (t >> 6);
    if (nn >= n) return;
    int hd = l >> 3;                       // head of channel 2l (== head of 2l+1)
    int beg = row_start[nn], end = row_start[nn + 1];
    float aldv = ald[(size_t)nn * 8 + hd];
    float aX0 = 0.f, aY0 = 0.f, aX1 = 0.f, aY1 = 0.f, den0 = 0.f, den1 = 0.f;
    int i = beg;
    for (; i + 2 <= end; i += 2) {
        int s0 = csr_src[i];
        int s1 = csr_src[i + 1];
        float e0 = als[(size_t)s0 * 8 + hd];
        float e1 = als[(size_t)s1 * 8 + hd];
        unsigned v0 = hu[(size_t)s0 * 64 + l];
        unsigned v1 = hu[(size_t)s1 * 64 + l];
        e0 += aldv; e0 = (e0 < 0.f) ? SLOPE * e0 : e0;
        e1 += aldv; e1 = (e1 < 0.f) ? SLOPE * e1 : e1;
        float x0 = __expf(e0);
        float x1 = __expf(e1);
        den0 += x0; den1 += x1;
        aX0 = fmaf(x0, __uint_as_float(v0 << 16), aX0);
        aY0 = fmaf(x0, __uint_as_float(v0 & 0xFFFF0000u), aY0);
        aX1 = fmaf(x1, __uint_as_float(v1 << 16), aX1);
        aY1 = fmaf(x1, __uint_as_float(v1 & 0xFFFF0000u), aY1);
    }
    if (i < end) {
        int s0 = csr_src[i];
        float e0 = als[(size_t)s0 * 8 + hd] + aldv;
        unsigned v0 = hu[(size_t)s0 * 64 + l];
        e0 = (e0 < 0.f) ? SLOPE * e0 : e0;
        float x0 = __expf(e0);
        den0 += x0;
        aX0 = fmaf(x0, __uint_as_float(v0 << 16), aX0);
        aY0 = fmaf(x0, __uint_as_float(v0 & 0xFFFF0000u), aY0);
    }
    float inv = 1.f / (den0 + den1);
    float2 bv = *(const float2*)&bias[2 * l];
    float2 res;
    res.x = fmaxf((aX0 + aX1) * inv + bv.x, 0.f);
    res.y = fmaxf((aY0 + aY1) * inv + bv.y, 0.f);
    *(float2*)&out[(size_t)nn * 128 + 2 * l] = res;
}

// ---------------- Layer 2 GEMM: h2 = out1 @ W2 (128->16), + logits ----------------

__global__ __launch_bounds__(256) void k_gemm2(const float* __restrict__ x,
                                               const float* __restrict__ W,
                                               const float* __restrict__ a_src,
                                               const float* __restrict__ a_dst,
                                               float* __restrict__ h,
                                               float* __restrict__ als,
                                               float* __restrict__ ald, int n) {
    __shared__ float Wl[128 * 16];   // 8 KB
    __shared__ float xl[16][128];    // 8 KB
    int tid = threadIdx.x;
    for (int i = tid; i < 128 * 16; i += 256) Wl[i] = W[i];
    int base = blockIdx.x * 128;
    int nl = tid >> 4, c = tid & 15;
    for (int g = 0; g < 8; ++g) {
        int nb = base + g * 16;
        __syncthreads();
        if (nb + nl < n) {
            int kk = c * 8;
            *(float4*)&xl[nl][kk]     = *(const float4*)&x[(size_t)(nb + nl) * 128 + kk];
            *(float4*)&xl[nl][kk + 4] = *(const float4*)&x[(size_t)(nb + nl) * 128 + kk + 4];
        }
        __syncthreads();
        int nn = nb + nl;
        if (nn < n) {
            float acc = 0.f;
#pragma unroll 8
            for (int k = 0; k < 128; ++k)
                acc = fmaf(xl[nl][k], Wl[k * 16 + c], acc);
            h[(size_t)nn * 16 + c] = acc;
            float ps = acc * a_src[c];
            float pd = acc * a_dst[c];
            ps += __shfl_xor(ps, 1); ps += __shfl_xor(ps, 2);
            ps += __shfl_xor(ps, 4); ps += __shfl_xor(ps, 8);
            pd += __shfl_xor(pd, 1); pd += __shfl_xor(pd, 2);
            pd += __shfl_xor(pd, 4); pd += __shfl_xor(pd, 8);
            if (c == 0) { als[nn] = ps; ald[nn] = pd; }
        }
    }
}

// ---------------- Layer 2 aggregation ----------------

__global__ __launch_bounds__(256) void k_agg2(const float* __restrict__ h,
                                              const float* __restrict__ als,
                                              const float* __restrict__ ald,
                                              const float* __restrict__ bias,
                                              const int* __restrict__ row_start,
                                              const int* __restrict__ csr_src,
                                              float* __restrict__ out, int n) {
    int tid = threadIdx.x;
    int nn = blockIdx.x * 16 + (tid >> 4);
    int c = tid & 15;
    if (nn >= n) return;
    int beg = row_start[nn], end = row_start[nn + 1];
    float aldv = ald[nn];
    float acc0 = 0.f, acc1 = 0.f, den0 = 0.f, den1 = 0.f;
    int i = beg;
    for (; i + 2 <= end; i += 2) {
        int s0 = csr_src[i];
        int s1 = csr_src[i + 1];
        float a0 = als[s0];
        float a1 = als[s1];
        float v0 = h[(size_t)s0 * 16 + c];
        float v1 = h[(size_t)s1 * 16 + c];
        float e0 = a0 + aldv; e0 = (e0 < 0.f) ? SLOPE * e0 : e0;
        float e1 = a1 + aldv; e1 = (e1 < 0.f) ? SLOPE * e1 : e1;
        float x0 = __expf(e0);
        float x1 = __expf(e1);
        den0 += x0; den1 += x1;
        acc0 = fmaf(x0, v0, acc0);
        acc1 = fmaf(x1, v1, acc1);
    }
    if (i < end) {
        int s0 = csr_src[i];
        float e0 = als[s0] + aldv;
        e0 = (e0 < 0.f) ? SLOPE * e0 : e0;
        float x0 = __expf(e0);
        den0 += x0;
        acc0 = fmaf(x0, h[(size_t)s0 * 16 + c], acc0);
    }
    out[(size_t)nn * 16 + c] = fmaxf((acc0 + acc1) / (den0 + den1) + bias[c], 0.f);
}

// ---------------- launch ----------------

extern "C" void kernel_launch(void* const* d_in, const int* in_sizes, int n_in,
                              void* d_out, int out_size, void* d_ws, size_t ws_size,
                              hipStream_t stream) {
    const float* x   = (const float*)d_in[0];
    const int*   ei  = (const int*)d_in[1];
    const float* W1  = (const float*)d_in[2];
    const float* as1 = (const float*)d_in[3];
    const float* ad1 = (const float*)d_in[4];
    const float* b1  = (const float*)d_in[5];
    const float* W2  = (const float*)d_in[6];
    const float* as2 = (const float*)d_in[7];
    const float* ad2 = (const float*)d_in[8];
    const float* b2  = (const float*)d_in[9];

    int N = in_sizes[0] / NFEAT;
    int E = in_sizes[1] / 2;
    const int* srcp = ei;
    const int* dstp = ei + E;
    int nb_scan = (N + SCAN_TILE - 1) / SCAN_TILE;

    char* ws = (char*)d_ws;
    size_t off = 0;
    auto take = [&](size_t bytes) -> char* {
        char* p = ws + off;
        off = (off + bytes + 255) & ~(size_t)255;
        return p;
    };
    int*            row_start = (int*)take((size_t)(N + 1) * 4);
    int*            cursor    = (int*)take((size_t)N * 4);
    int*            part      = (int*)take((size_t)nb_scan * 4);
    int*            csr       = (int*)take((size_t)(E + N) * 4);
    unsigned short* xb        = (unsigned short*)take((size_t)N * 128 * 2);
    unsigned*       Wt        = (unsigned*)take((size_t)128 * 64 * 4);
    unsigned short* Aat       = (unsigned short*)take((size_t)16 * 128 * 2);
    unsigned*       h1u       = (unsigned*)take((size_t)N * 64 * 4);   // bf16x2
    float*          als1      = (float*)take((size_t)N * 8 * 4);
    float*          ald1      = (float*)take((size_t)N * 8 * 4);
    float*          out1      = (float*)take((size_t)N * 128 * 4);
    float*          h2        = (float*)take((size_t)N * 16 * 4);
    float*          als2      = (float*)take((size_t)N * 4);
    float*          ald2      = (float*)take((size_t)N * 4);

    k_init_deg<<<(N + 255) / 256, 256, 0, stream>>>(cursor, N);
    k_hist<<<(E + 255) / 256, 256, 0, stream>>>(dstp, E, cursor);
    k_scan_part<<<nb_scan, 256, 0, stream>>>(cursor, part, N);
    k_scan_top<<<1, 64, 0, stream>>>(part, nb_scan, row_start, N);
    k_scan_apply<<<nb_scan, 256, 0, stream>>>(cursor, part, row_start, N);
    k_scatter<<<(E + N + 255) / 256, 256, 0, stream>>>(srcp, dstp, E, N, cursor, csr);

    k_cast_x<<<(N * 16 + 255) / 256, 256, 0, stream>>>(x, (unsigned*)xb, N * 16);
    k_prep<<<1, 256, 0, stream>>>(W1, as1, ad1, Wt, Aat);
    k_gemm1m<<<(N + 127) / 128, 256, 0, stream>>>(xb, (const unsigned short*)Wt, Aat,
                                                  h1u, als1, ald1, N);
    k_agg1<<<(N + 1) / 2, 128, 0, stream>>>(h1u, als1, ald1, b1, row_start, csr, out1, N);
    k_gemm2<<<(N + 127) / 128, 256, 0, stream>>>(out1, W2, as2, ad2, h2, als2, ald2, N);
    k_agg2<<<(N + 15) / 16, 256, 0, stream>>>(h2, als2, ald2, b2, row_start, csr, (float*)d_out, N);
}

// Round 5
// 207.260 us; speedup vs baseline: 1.9968x; 1.1830x over previous
//
#include <hip/hip_runtime.h>

#define NFEAT 128
#define HEADS 8
#define NHID 16
#define SLOPE 0.2f
#define SCAN_TILE 2048   // 256 threads * 8 items

typedef short s8v __attribute__((ext_vector_type(8)));   // 8 bf16 (4 VGPRs) MFMA A/B frag
typedef float f4v __attribute__((ext_vector_type(4)));   // 4 f32 MFMA C/D frag

// bf16 round-to-nearest-even pack helpers
__device__ __forceinline__ unsigned bf16rne(float f) {
    unsigned u = __float_as_uint(f);
    return (u + 0x7FFFu + ((u >> 16) & 1u)) >> 16;
}
__device__ __forceinline__ unsigned pack2bf16(float a, float b) {
    return bf16rne(a) | (bf16rne(b) << 16);
}
// build an 8-element bf16 A/B fragment from 8 consecutive f32
__device__ __forceinline__ s8v frag_from_f32(const float* p) {
    float4 q0 = *(const float4*)p;
    float4 q1 = *(const float4*)(p + 4);
    union { s8v v; unsigned u[4]; } r;
    r.u[0] = pack2bf16(q0.x, q0.y); r.u[1] = pack2bf16(q0.z, q0.w);
    r.u[2] = pack2bf16(q1.x, q1.y); r.u[3] = pack2bf16(q1.z, q1.w);
    return r.v;
}

// ---------------- CSR build ----------------

__global__ void k_init_deg(int* __restrict__ cursor, int n) {
    int i = blockIdx.x * blockDim.x + threadIdx.x;
    if (i < n) cursor[i] = 1;   // self-loop contributes 1 to every node's in-degree
}

__global__ void k_hist(const int* __restrict__ dst, int E, int* __restrict__ cursor) {
    int i = blockIdx.x * blockDim.x + threadIdx.x;
    if (i < E) atomicAdd(&cursor[dst[i]], 1);
}

// phase 1: per-block tile sums
__global__ __launch_bounds__(256) void k_scan_part(const int* __restrict__ deg,
                                                   int* __restrict__ part, int n) {
    __shared__ int sh[256];
    int t = threadIdx.x;
    int base = blockIdx.x * SCAN_TILE + t * 8;
    int s = 0;
#pragma unroll
    for (int j = 0; j < 8; ++j) { int i = base + j; if (i < n) s += deg[i]; }
    sh[t] = s;
    __syncthreads();
    for (int off = 128; off > 0; off >>= 1) {
        if (t < off) sh[t] += sh[t + off];
        __syncthreads();
    }
    if (t == 0) part[blockIdx.x] = sh[0];
}

// phase 2: single small block scans the partials (exclusive, in place); writes total
__global__ __launch_bounds__(64) void k_scan_top(int* __restrict__ part, int nb,
                                                 int* __restrict__ row_start, int n) {
    __shared__ int sh[64];
    int t = threadIdx.x;
    int v = (t < nb) ? part[t] : 0;
    sh[t] = v;
    __syncthreads();
    for (int off = 1; off < 64; off <<= 1) {
        int u = (t >= off) ? sh[t - off] : 0;
        __syncthreads();
        sh[t] += u;
        __syncthreads();
    }
    if (t < nb) part[t] = (t > 0) ? sh[t - 1] : 0;
    if (t == 0) row_start[n] = sh[63];
}

// phase 3: per-block exclusive scan + offset -> row_start, cursor
__global__ __launch_bounds__(256) void k_scan_apply(int* __restrict__ deg,
                                                    const int* __restrict__ part,
                                                    int* __restrict__ row_start, int n) {
    __shared__ int sh[256];
    int t = threadIdx.x;
    int base = blockIdx.x * SCAN_TILE + t * 8;
    int v[8];
    int s = 0;
#pragma unroll
    for (int j = 0; j < 8; ++j) { int i = base + j; v[j] = (i < n) ? deg[i] : 0; s += v[j]; }
    sh[t] = s;
    __syncthreads();
    for (int off = 1; off < 256; off <<= 1) {
        int u = (t >= off) ? sh[t - off] : 0;
        __syncthreads();
        sh[t] += u;
        __syncthreads();
    }
    int run = part[blockIdx.x] + ((t > 0) ? sh[t - 1] : 0);
#pragma unroll
    for (int j = 0; j < 8; ++j) {
        int i = base + j;
        if (i < n) { row_start[i] = run; deg[i] = run; run += v[j]; }
    }
}

__global__ void k_scatter(const int* __restrict__ src, const int* __restrict__ dst,
                          int E, int n, int* __restrict__ cursor, int* __restrict__ csr_src) {
    int i = blockIdx.x * blockDim.x + threadIdx.x;
    int total = E + n;
    if (i >= total) return;
    int s, d;
    if (i < E) { s = src[i]; d = dst[i]; }
    else       { s = d = i - E; }          // self loop
    int pos = atomicAdd(&cursor[d], 1);
    csr_src[pos] = s;
}

// ---------------- weight prep (parallel): Wt1[128c][128k], Aat1[16][128], W2t[16c][128k] ----------------
// Aat1 rows 0..7 = a_src1 block-diagonal (row j gets a_src[k] iff k>>4==j), rows 8..15 a_dst1.

__global__ __launch_bounds__(256) void k_prep(const float* __restrict__ W1,
                                              const float* __restrict__ as1,
                                              const float* __restrict__ ad1,
                                              const float* __restrict__ W2,
                                              unsigned* __restrict__ Wt1,          // [128][64] u32
                                              unsigned short* __restrict__ Aat1,   // [16][128]
                                              unsigned* __restrict__ W2t) {        // [16][64] u32
    int t = blockIdx.x * 256 + threadIdx.x;
    if (t < 8192) {                       // Wt1: word idx = c*64 + m, holds W1[2m][c],W1[2m+1][c]
        int c = t >> 6, m = t & 63;
        int k = 2 * m;
        Wt1[t] = pack2bf16(W1[k * 128 + c], W1[(k + 1) * 128 + c]);
    } else if (t < 10240) {               // Aat1
        int idx = t - 8192;
        int j = idx >> 7, k = idx & 127;
        float v = 0.f;
        if (j < 8)  { if ((k >> 4) == j)     v = as1[k]; }
        else        { if ((k >> 4) == j - 8) v = ad1[k]; }
        Aat1[idx] = (unsigned short)bf16rne(v);
    } else if (t < 11264) {               // W2t: word idx = c*64 + m, holds W2[2m][c],W2[2m+1][c]
        int idx = t - 10240;
        int c = idx >> 6, m = idx & 63;
        int k = 2 * m;
        W2t[idx] = pack2bf16(W2[k * 16 + c], W2[(k + 1) * 16 + c]);
    }
}

// ---------------- Layer 1 GEMM via MFMA: h1(bf16) = x @ W1, logits via 2nd MFMA ----------------
// 256 threads = 4 waves; wave handles 32 nodes (2 A-tiles of 16), all 128 cols (8 col-tiles).
// A-frag: lane l holds A[row=l&15][k=8*(l>>4)+i]; B-frag: B[k][col=l&15];
// C/D: lane l holds D[row=4*(l>>4)+j][col=l&15]  (m89-verified layout).

__global__ __launch_bounds__(256) void k_gemm1m(const float* __restrict__ xf,
                                                const unsigned short* __restrict__ Wt,
                                                const unsigned short* __restrict__ Aat,
                                                unsigned* __restrict__ h1u,     // [n][64] bf16x2
                                                float* __restrict__ als,
                                                float* __restrict__ ald, int n) {
    __shared__ unsigned hl[4][32 * 64];   // per-wave h repack (swizzled), 32 KB
    int tid = threadIdx.x;
    int w = tid >> 6, l = tid & 63;
    int l15 = l & 15, lq = l >> 4;
    int wbase = blockIdx.x * 128 + w * 32;
    f4v acc[2][8] = {};
    int r0 = min(wbase + l15, n - 1);
    int r1 = min(wbase + 16 + l15, n - 1);
#pragma unroll
    for (int kb = 0; kb < 4; ++kb) {
        int ko = kb * 32 + lq * 8;
        s8v a0 = frag_from_f32(&xf[(size_t)r0 * 128 + ko]);
        s8v a1 = frag_from_f32(&xf[(size_t)r1 * 128 + ko]);
#pragma unroll
        for (int cg = 0; cg < 8; ++cg) {
            s8v b = *(const s8v*)&Wt[(size_t)(cg * 16 + l15) * 128 + ko];
            acc[0][cg] = __builtin_amdgcn_mfma_f32_16x16x32_bf16(a0, b, acc[0][cg], 0, 0, 0);
            acc[1][cg] = __builtin_amdgcn_mfma_f32_16x16x32_bf16(a1, b, acc[1][cg], 0, 0, 0);
        }
    }
    // pack h to bf16 pairs -> swizzled LDS (granule16 g' = g ^ (node&15))
    unsigned* myl = hl[w];
#pragma unroll
    for (int T = 0; T < 2; ++T) {
#pragma unroll
        for (int cg = 0; cg < 8; ++cg) {
#pragma unroll
            for (int j = 0; j < 4; ++j) {
                float v = acc[T][cg][j];
                float vo = __shfl_xor(v, 1);
                if ((l15 & 1) == 0) {
                    int nd = T * 16 + lq * 4 + j;
                    int wd = cg * 8 + (l15 >> 1);
                    int widx = nd * 64 + (((wd >> 2) ^ (nd & 15)) << 2) + (wd & 3);
                    myl[widx] = pack2bf16(v, vo);
                }
            }
        }
    }
    __syncthreads();
    // coalesced h1 store: quarter-wave covers one node's 256 B
#pragma unroll
    for (int it = 0; it < 8; ++it) {
        int nd = it * 4 + lq;
        int node = wbase + nd;
        uint4 vv = *(const uint4*)&myl[nd * 64 + ((l15 ^ (nd & 15)) << 2)];
        if (node < n) *(uint4*)&h1u[(size_t)node * 64 + l15 * 4] = vv;
    }
    // attention logits: D2 = h_tile @ Aat^T  (16x16, K=128)
#pragma unroll
    for (int T = 0; T < 2; ++T) {
        f4v acca = {};
#pragma unroll
        for (int kb = 0; kb < 4; ++kb) {
            int nd = T * 16 + l15;
            s8v ah = *(const s8v*)&myl[nd * 64 + (((kb * 4 + lq) ^ (nd & 15)) << 2)];
            s8v bb = *(const s8v*)&Aat[l15 * 128 + kb * 32 + lq * 8];
            acca = __builtin_amdgcn_mfma_f32_16x16x32_bf16(ah, bb, acca, 0, 0, 0);
        }
#pragma unroll
        for (int j = 0; j < 4; ++j) {
            int node = wbase + T * 16 + lq * 4 + j;
            if (node < n) {
                if (l15 < 8) als[(size_t)node * 8 + l15] = acca[j];
                else         ald[(size_t)node * 8 + (l15 - 8)] = acca[j];
            }
        }
    }
}

// ---------------- Layer 1 aggregation ----------------
// 256 threads = 4 nodes x 64 lanes; lane l handles channels 2l,2l+1 (one bf16x2 word).
// 4-way unrolled edge loop, int4 broadcast index loads -> 4 independent gather chains.

__global__ __launch_bounds__(256) void k_agg1(const unsigned* __restrict__ hu,
                                              const float* __restrict__ als,
                                              const float* __restrict__ ald,
                                              const float* __restrict__ bias,
                                              const int* __restrict__ row_start,
                                              const int* __restrict__ csr_src,
                                              unsigned* __restrict__ out1u, int n) {
    int t = threadIdx.x;
    int l = t & 63;
    int nn = blockIdx.x * 4 + (t >> 6);
    if (nn >= n) return;
    int hd = l >> 3;                       // head of channel 2l
    int beg = row_start[nn], end = row_start[nn + 1];
    float aldv = ald[(size_t)nn * 8 + hd];
    float aX[4] = {0.f, 0.f, 0.f, 0.f}, aY[4] = {0.f, 0.f, 0.f, 0.f};
    float dn[4] = {0.f, 0.f, 0.f, 0.f};
    int i = beg;
    // peel to 16B alignment of csr_src[i]
    for (; i < end && (i & 3); ++i) {
        int s = csr_src[i];
        float e = als[(size_t)s * 8 + hd] + aldv;
        unsigned v = hu[(size_t)s * 64 + l];
        e = (e < 0.f) ? SLOPE * e : e;
        float xv = __expf(e);
        dn[0] += xv;
        aX[0] = fmaf(xv, __uint_as_float(v << 16), aX[0]);
        aY[0] = fmaf(xv, __uint_as_float(v & 0xFFFF0000u), aY[0]);
    }
    for (; i + 4 <= end; i += 4) {
        int4 s4 = *(const int4*)&csr_src[i];
        float e0 = als[(size_t)s4.x * 8 + hd];
        float e1 = als[(size_t)s4.y * 8 + hd];
        float e2 = als[(size_t)s4.z * 8 + hd];
        float e3 = als[(size_t)s4.w * 8 + hd];
        unsigned v0 = hu[(size_t)s4.x * 64 + l];
        unsigned v1 = hu[(size_t)s4.y * 64 + l];
        unsigned v2 = hu[(size_t)s4.z * 64 + l];
        unsigned v3 = hu[(size_t)s4.w * 64 + l];
        e0 += aldv; e0 = (e0 < 0.f) ? SLOPE * e0 : e0;
        e1 += aldv; e1 = (e1 < 0.f) ? SLOPE * e1 : e1;
        e2 += aldv; e2 = (e2 < 0.f) ? SLOPE * e2 : e2;
        e3 += aldv; e3 = (e3 < 0.f) ? SLOPE * e3 : e3;
        float x0 = __expf(e0), x1 = __expf(e1), x2 = __expf(e2), x3 = __expf(e3);
        dn[0] += x0; dn[1] += x1; dn[2] += x2; dn[3] += x3;
        aX[0] = fmaf(x0, __uint_as_float(v0 << 16), aX[0]);
        aY[0] = fmaf(x0, __uint_as_float(v0 & 0xFFFF0000u), aY[0]);
        aX[1] = fmaf(x1, __uint_as_float(v1 << 16), aX[1]);
        aY[1] = fmaf(x1, __uint_as_float(v1 & 0xFFFF0000u), aY[1]);
        aX[2] = fmaf(x2, __uint_as_float(v2 << 16), aX[2]);
        aY[2] = fmaf(x2, __uint_as_float(v2 & 0xFFFF0000u), aY[2]);
        aX[3] = fmaf(x3, __uint_as_float(v3 << 16), aX[3]);
        aY[3] = fmaf(x3, __uint_as_float(v3 & 0xFFFF0000u), aY[3]);
    }
    for (; i < end; ++i) {
        int s = csr_src[i];
        float e = als[(size_t)s * 8 + hd] + aldv;
        unsigned v = hu[(size_t)s * 64 + l];
        e = (e < 0.f) ? SLOPE * e : e;
        float xv = __expf(e);
        dn[0] += xv;
        aX[0] = fmaf(xv, __uint_as_float(v << 16), aX[0]);
        aY[0] = fmaf(xv, __uint_as_float(v & 0xFFFF0000u), aY[0]);
    }
    float inv = 1.f / (dn[0] + dn[1] + dn[2] + dn[3]);
    float2 bv = *(const float2*)&bias[2 * l];
    float rx = fmaxf((aX[0] + aX[1] + aX[2] + aX[3]) * inv + bv.x, 0.f);
    float ry = fmaxf((aY[0] + aY[1] + aY[2] + aY[3]) * inv + bv.y, 0.f);
    out1u[(size_t)nn * 64 + l] = pack2bf16(rx, ry);   // layer-2 input is bf16
}

// ---------------- Layer 2 GEMM via MFMA: h2 = out1(bf16) @ W2, logits via shuffle ----------------
// 4 waves x 32 nodes; single 16-col group. D: lane l holds D[row=4*(l>>4)+j][col=l&15].

__global__ __launch_bounds__(256) void k_gemm2m(const unsigned short* __restrict__ o1,
                                                const unsigned short* __restrict__ W2t,
                                                const float* __restrict__ as2,
                                                const float* __restrict__ ad2,
                                                float* __restrict__ h2,
                                                float* __restrict__ als,
                                                float* __restrict__ ald, int n) {
    int tid = threadIdx.x;
    int w = tid >> 6, l = tid & 63;
    int l15 = l & 15, lq = l >> 4;
    int wbase = blockIdx.x * 128 + w * 32;
    f4v acc[2] = {};
    int r0 = min(wbase + l15, n - 1);
    int r1 = min(wbase + 16 + l15, n - 1);
#pragma unroll
    for (int kb = 0; kb < 4; ++kb) {
        int ko = kb * 32 + lq * 8;
        s8v a0 = *(const s8v*)&o1[(size_t)r0 * 128 + ko];
        s8v a1 = *(const s8v*)&o1[(size_t)r1 * 128 + ko];
        s8v b  = *(const s8v*)&W2t[(size_t)l15 * 128 + ko];
        acc[0] = __builtin_amdgcn_mfma_f32_16x16x32_bf16(a0, b, acc[0], 0, 0, 0);
        acc[1] = __builtin_amdgcn_mfma_f32_16x16x32_bf16(a1, b, acc[1], 0, 0, 0);
    }
    float asv = as2[l15], adv = ad2[l15];
#pragma unroll
    for (int T = 0; T < 2; ++T) {
#pragma unroll
        for (int j = 0; j < 4; ++j) {
            int node = wbase + T * 16 + lq * 4 + j;
            float hv = acc[T][j];
            float ps = hv * asv, pd = hv * adv;
            ps += __shfl_xor(ps, 1); ps += __shfl_xor(ps, 2);
            ps += __shfl_xor(ps, 4); ps += __shfl_xor(ps, 8);
            pd += __shfl_xor(pd, 1); pd += __shfl_xor(pd, 2);
            pd += __shfl_xor(pd, 4); pd += __shfl_xor(pd, 8);
            if (node < n) {
                h2[(size_t)node * 16 + l15] = hv;
                if (l15 == 0) { als[node] = ps; ald[node] = pd; }
            }
        }
    }
}

// ---------------- Layer 2 aggregation (unroll 4) ----------------

__global__ __launch_bounds__(256) void k_agg2(const float* __restrict__ h,
                                              const float* __restrict__ als,
                                              const float* __restrict__ ald,
                                              const float* __restrict__ bias,
                                              const int* __restrict__ row_start,
                                              const int* __restrict__ csr_src,
                                              float* __restrict__ out, int n) {
    int tid = threadIdx.x;
    int nn = blockIdx.x * 16 + (tid >> 4);
    int c = tid & 15;
    if (nn >= n) return;
    int beg = row_start[nn], end = row_start[nn + 1];
    float aldv = ald[nn];
    float ac[4] = {0.f, 0.f, 0.f, 0.f}, dn[4] = {0.f, 0.f, 0.f, 0.f};
    int i = beg;
    for (; i < end && (i & 3); ++i) {
        int s = csr_src[i];
        float e = als[s] + aldv;
        e = (e < 0.f) ? SLOPE * e : e;
        float xv = __expf(e);
        dn[0] += xv;
        ac[0] = fmaf(xv, h[(size_t)s * 16 + c], ac[0]);
    }
    for (; i + 4 <= end; i += 4) {
        int4 s4 = *(const int4*)&csr_src[i];
        float e0 = als[s4.x], e1 = als[s4.y], e2 = als[s4.z], e3 = als[s4.w];
        float v0 = h[(size_t)s4.x * 16 + c];
        float v1 = h[(size_t)s4.y * 16 + c];
        float v2 = h[(size_t)s4.z * 16 + c];
        float v3 = h[(size_t)s4.w * 16 + c];
        e0 += aldv; e0 = (e0 < 0.f) ? SLOPE * e0 : e0;
        e1 += aldv; e1 = (e1 < 0.f) ? SLOPE * e1 : e1;
        e2 += aldv; e2 = (e2 < 0.f) ? SLOPE * e2 : e2;
        e3 += aldv; e3 = (e3 < 0.f) ? SLOPE * e3 : e3;
        float x0 = __expf(e0), x1 = __expf(e1), x2 = __expf(e2), x3 = __expf(e3);
        dn[0] += x0; dn[1] += x1; dn[2] += x2; dn[3] += x3;
        ac[0] = fmaf(x0, v0, ac[0]);
        ac[1] = fmaf(x1, v1, ac[1]);
        ac[2] = fmaf(x2, v2, ac[2]);
        ac[3] = fmaf(x3, v3, ac[3]);
    }
    for (; i < end; ++i) {
        int s = csr_src[i];
        float e = als[s] + aldv;
        e = (e < 0.f) ? SLOPE * e : e;
        float xv = __expf(e);
        dn[0] += xv;
        ac[0] = fmaf(xv, h[(size_t)s * 16 + c], ac[0]);
    }
    out[(size_t)nn * 16 + c] =
        fmaxf((ac[0] + ac[1] + ac[2] + ac[3]) / (dn[0] + dn[1] + dn[2] + dn[3]) + bias[c], 0.f);
}

// ---------------- launch ----------------

extern "C" void kernel_launch(void* const* d_in, const int* in_sizes, int n_in,
                              void* d_out, int out_size, void* d_ws, size_t ws_size,
                              hipStream_t stream) {
    const float* x   = (const float*)d_in[0];
    const int*   ei  = (const int*)d_in[1];
    const float* W1  = (const float*)d_in[2];
    const float* as1 = (const float*)d_in[3];
    const float* ad1 = (const float*)d_in[4];
    const float* b1  = (const float*)d_in[5];
    const float* W2  = (const float*)d_in[6];
    const float* as2 = (const float*)d_in[7];
    const float* ad2 = (const float*)d_in[8];
    const float* b2  = (const float*)d_in[9];

    int N = in_sizes[0] / NFEAT;
    int E = in_sizes[1] / 2;
    const int* srcp = ei;
    const int* dstp = ei + E;
    int nb_scan = (N + SCAN_TILE - 1) / SCAN_TILE;

    char* ws = (char*)d_ws;
    size_t off = 0;
    auto take = [&](size_t bytes) -> char* {
        char* p = ws + off;
        off = (off + bytes + 255) & ~(size_t)255;
        return p;
    };
    int*            row_start = (int*)take((size_t)(N + 1) * 4);
    int*            cursor    = (int*)take((size_t)N * 4);
    int*            part      = (int*)take((size_t)nb_scan * 4);
    int*            csr       = (int*)take((size_t)(E + N) * 4);
    unsigned*       Wt1       = (unsigned*)take((size_t)128 * 64 * 4);
    unsigned short* Aat1      = (unsigned short*)take((size_t)16 * 128 * 2);
    unsigned*       W2t       = (unsigned*)take((size_t)16 * 64 * 4);
    unsigned*       h1u       = (unsigned*)take((size_t)N * 64 * 4);   // bf16x2
    float*          als1      = (float*)take((size_t)N * 8 * 4);
    float*          ald1      = (float*)take((size_t)N * 8 * 4);
    unsigned*       out1u     = (unsigned*)take((size_t)N * 64 * 4);   // bf16x2
    float*          h2        = (float*)take((size_t)N * 16 * 4);
    float*          als2      = (float*)take((size_t)N * 4);
    float*          ald2      = (float*)take((size_t)N * 4);

    k_init_deg<<<(N + 255) / 256, 256, 0, stream>>>(cursor, N);
    k_hist<<<(E + 255) / 256, 256, 0, stream>>>(dstp, E, cursor);
    k_scan_part<<<nb_scan, 256, 0, stream>>>(cursor, part, N);
    k_scan_top<<<1, 64, 0, stream>>>(part, nb_scan, row_start, N);
    k_scan_apply<<<nb_scan, 256, 0, stream>>>(cursor, part, row_start, N);
    k_scatter<<<(E + N + 255) / 256, 256, 0, stream>>>(srcp, dstp, E, N, cursor, csr);

    k_prep<<<44, 256, 0, stream>>>(W1, as1, ad1, W2, Wt1, Aat1, W2t);
    k_gemm1m<<<(N + 127) / 128, 256, 0, stream>>>(x, (const unsigned short*)Wt1, Aat1,
                                                  h1u, als1, ald1, N);
    k_agg1<<<(N + 3) / 4, 256, 0, stream>>>(h1u, als1, ald1, b1, row_start, csr, out1u, N);
    k_gemm2m<<<(N + 127) / 128, 256, 0, stream>>>((const unsigned short*)out1u,
                                                  (const unsigned short*)W2t,
                                                  as2, ad2, h2, als2, ald2, N);
    k_agg2<<<(N + 15) / 16, 256, 0, stream>>>(h2, als2, ald2, b2, row_start, csr, (float*)d_out, N);
}

// Round 6
// 152.213 us; speedup vs baseline: 2.7189x; 1.3616x over previous
//
#include <hip/hip_runtime.h>

#define NFEAT 128
#define HEADS 8
#define NHID 16
#define SLOPE 0.2f
#define BSH 8            // 256 dst nodes per bucket; NBUCK = ceil(N/256) <= 256 (N <= 65536)

typedef short s8v __attribute__((ext_vector_type(8)));   // 8 bf16 (4 VGPRs) MFMA A/B frag
typedef float f4v __attribute__((ext_vector_type(4)));   // 4 f32 MFMA C/D frag

// bf16 round-to-nearest-even pack helpers
__device__ __forceinline__ unsigned bf16rne(float f) {
    unsigned u = __float_as_uint(f);
    return (u + 0x7FFFu + ((u >> 16) & 1u)) >> 16;
}
__device__ __forceinline__ unsigned pack2bf16(float a, float b) {
    return bf16rne(a) | (bf16rne(b) << 16);
}
// build an 8-element bf16 A/B fragment from 8 consecutive f32
__device__ __forceinline__ s8v frag_from_f32(const float* p) {
    float4 q0 = *(const float4*)p;
    float4 q1 = *(const float4*)(p + 4);
    union { s8v v; unsigned u[4]; } r;
    r.u[0] = pack2bf16(q0.x, q0.y); r.u[1] = pack2bf16(q0.z, q0.w);
    r.u[2] = pack2bf16(q1.x, q1.y); r.u[3] = pack2bf16(q1.z, q1.w);
    return r.v;
}

// ---------------- bucketed CSR build ----------------

__global__ void k_zero(int* __restrict__ p, int m) {
    int i = blockIdx.x * blockDim.x + threadIdx.x;
    if (i < m) p[i] = 0;
}

// coarse histogram of dst>>BSH (LDS-staged, one global atomic per bucket per block)
__global__ __launch_bounds__(256) void k_bhist(const int* __restrict__ dst, int E,
                                               int* __restrict__ bcount) {
    __shared__ int h[256];
    int t = threadIdx.x;
    h[t] = 0;
    __syncthreads();
    int stride = gridDim.x * 256;
    for (int i = blockIdx.x * 256 + t; i < E; i += stride)
        atomicAdd(&h[dst[i] >> BSH], 1);
    __syncthreads();
    int v = h[t];
    if (v) atomicAdd(&bcount[t], v);
}

// exclusive scan of bucket counts -> pair_start, pair_cursor; also row_start[n]
__global__ __launch_bounds__(256) void k_bscan(const int* __restrict__ bcount,
                                               int* __restrict__ pair_start,
                                               int* __restrict__ pair_cursor,
                                               int* __restrict__ row_start,
                                               int E, int n) {
    __shared__ int sh[256];
    int t = threadIdx.x;
    int nb = (n + 255) >> BSH;
    int v = (t < nb) ? bcount[t] : 0;
    sh[t] = v;
    __syncthreads();
    for (int off = 1; off < 256; off <<= 1) {
        int u = (t >= off) ? sh[t - off] : 0;
        __syncthreads();
        sh[t] += u;
        __syncthreads();
    }
    int excl = sh[t] - v;
    pair_start[t] = excl;
    pair_cursor[t] = excl;
    if (t == 0) row_start[n] = E + n;
}

// partition edges into bucket-contiguous (src,dst) pair segments
__global__ __launch_bounds__(256) void k_bscatter(const int* __restrict__ src,
                                                  const int* __restrict__ dst,
                                                  int E, int chunk,
                                                  int* __restrict__ pair_cursor,
                                                  uint2* __restrict__ pairs) {
    __shared__ int cnt[256], base[256];
    int t = threadIdx.x;
    int beg = blockIdx.x * chunk;
    int end = min(beg + chunk, E);
    if (beg >= end) return;
    cnt[t] = 0;
    __syncthreads();
    for (int i = beg + t; i < end; i += 256)
        atomicAdd(&cnt[dst[i] >> BSH], 1);
    __syncthreads();
    int c = cnt[t];
    base[t] = c ? atomicAdd(&pair_cursor[t], c) : 0;
    __syncthreads();
    cnt[t] = 0;
    __syncthreads();
    for (int i = beg + t; i < end; i += 256) {
        int d = dst[i];
        int b = d >> BSH;
        int ofs = atomicAdd(&cnt[b], 1);
        pairs[base[b] + ofs] = make_uint2((unsigned)src[i], (unsigned)d);
    }
}

// per-bucket: degree count (+1 self loop) -> row_start; scatter csr via LDS cursors
__global__ __launch_bounds__(256) void k_bucket_csr(const uint2* __restrict__ pairs,
                                                    const int* __restrict__ pair_start,
                                                    const int* __restrict__ bcount,
                                                    int* __restrict__ row_start,
                                                    int* __restrict__ csr, int n) {
    __shared__ int deg[256], sc[256];
    int b = blockIdx.x, t = threadIdx.x;
    int d0 = b << BSH;
    int nd = min(256, n - d0);
    deg[t] = (t < nd) ? 1 : 0;   // self loop
    __syncthreads();
    int pbeg = pair_start[b], pend = pbeg + bcount[b];
    for (int i = pbeg + t; i < pend; i += 256)
        atomicAdd(&deg[pairs[i].y - d0], 1);
    __syncthreads();
    int v = deg[t];
    sc[t] = v;
    __syncthreads();
    for (int off = 1; off < 256; off <<= 1) {
        int u = (t >= off) ? sc[t - off] : 0;
        __syncthreads();
        sc[t] += u;
        __syncthreads();
    }
    int excl = sc[t] - v;
    int cbase = pair_start[b] + d0;        // csr base of this bucket
    if (t < nd) row_start[d0 + t] = cbase + excl;
    __syncthreads();
    deg[t] = excl;                          // reuse as cursor
    __syncthreads();
    if (t < nd) {                           // self loop entry
        int pos = atomicAdd(&deg[t], 1);
        csr[cbase + pos] = d0 + t;
    }
    for (int i = pbeg + t; i < pend; i += 256) {
        uint2 p = pairs[i];
        int pos = atomicAdd(&deg[p.y - d0], 1);
        csr[cbase + pos] = (int)p.x;
    }
}

// ---------------- weight prep (parallel): Wt1[128c][128k], Aat1[16][128], W2t[16c][128k] ----------------

__global__ __launch_bounds__(256) void k_prep(const float* __restrict__ W1,
                                              const float* __restrict__ as1,
                                              const float* __restrict__ ad1,
                                              const float* __restrict__ W2,
                                              unsigned* __restrict__ Wt1,          // [128][64] u32
                                              unsigned short* __restrict__ Aat1,   // [16][128]
                                              unsigned* __restrict__ W2t) {        // [16][64] u32
    int t = blockIdx.x * 256 + threadIdx.x;
    if (t < 8192) {
        int c = t >> 6, m = t & 63;
        int k = 2 * m;
        Wt1[t] = pack2bf16(W1[k * 128 + c], W1[(k + 1) * 128 + c]);
    } else if (t < 10240) {
        int idx = t - 8192;
        int j = idx >> 7, k = idx & 127;
        float v = 0.f;
        if (j < 8)  { if ((k >> 4) == j)     v = as1[k]; }
        else        { if ((k >> 4) == j - 8) v = ad1[k]; }
        Aat1[idx] = (unsigned short)bf16rne(v);
    } else if (t < 11264) {
        int idx = t - 10240;
        int c = idx >> 6, m = idx & 63;
        int k = 2 * m;
        W2t[idx] = pack2bf16(W2[k * 16 + c], W2[(k + 1) * 16 + c]);
    }
}

// ---------------- Layer 1 GEMM via MFMA: h1(bf16) = x @ W1, logits via 2nd MFMA ----------------

__global__ __launch_bounds__(256) void k_gemm1m(const float* __restrict__ xf,
                                                const unsigned short* __restrict__ Wt,
                                                const unsigned short* __restrict__ Aat,
                                                unsigned* __restrict__ h1u,     // [n][64] bf16x2
                                                float* __restrict__ als,
                                                float* __restrict__ ald, int n) {
    __shared__ unsigned hl[4][32 * 64];   // per-wave h repack (swizzled), 32 KB
    int tid = threadIdx.x;
    int w = tid >> 6, l = tid & 63;
    int l15 = l & 15, lq = l >> 4;
    int wbase = blockIdx.x * 128 + w * 32;
    f4v acc[2][8] = {};
    int r0 = min(wbase + l15, n - 1);
    int r1 = min(wbase + 16 + l15, n - 1);
#pragma unroll
    for (int kb = 0; kb < 4; ++kb) {
        int ko = kb * 32 + lq * 8;
        s8v a0 = frag_from_f32(&xf[(size_t)r0 * 128 + ko]);
        s8v a1 = frag_from_f32(&xf[(size_t)r1 * 128 + ko]);
#pragma unroll
        for (int cg = 0; cg < 8; ++cg) {
            s8v b = *(const s8v*)&Wt[(size_t)(cg * 16 + l15) * 128 + ko];
            acc[0][cg] = __builtin_amdgcn_mfma_f32_16x16x32_bf16(a0, b, acc[0][cg], 0, 0, 0);
            acc[1][cg] = __builtin_amdgcn_mfma_f32_16x16x32_bf16(a1, b, acc[1][cg], 0, 0, 0);
        }
    }
    unsigned* myl = hl[w];
#pragma unroll
    for (int T = 0; T < 2; ++T) {
#pragma unroll
        for (int cg = 0; cg < 8; ++cg) {
#pragma unroll
            for (int j = 0; j < 4; ++j) {
                float v = acc[T][cg][j];
                float vo = __shfl_xor(v, 1);
                if ((l15 & 1) == 0) {
                    int nd = T * 16 + lq * 4 + j;
                    int wd = cg * 8 + (l15 >> 1);
                    int widx = nd * 64 + (((wd >> 2) ^ (nd & 15)) << 2) + (wd & 3);
                    myl[widx] = pack2bf16(v, vo);
                }
            }
        }
    }
    __syncthreads();
#pragma unroll
    for (int it = 0; it < 8; ++it) {
        int nd = it * 4 + lq;
        int node = wbase + nd;
        uint4 vv = *(const uint4*)&myl[nd * 64 + ((l15 ^ (nd & 15)) << 2)];
        if (node < n) *(uint4*)&h1u[(size_t)node * 64 + l15 * 4] = vv;
    }
#pragma unroll
    for (int T = 0; T < 2; ++T) {
        f4v acca = {};
#pragma unroll
        for (int kb = 0; kb < 4; ++kb) {
            int nd = T * 16 + l15;
            s8v ah = *(const s8v*)&myl[nd * 64 + (((kb * 4 + lq) ^ (nd & 15)) << 2)];
            s8v bb = *(const s8v*)&Aat[l15 * 128 + kb * 32 + lq * 8];
            acca = __builtin_amdgcn_mfma_f32_16x16x32_bf16(ah, bb, acca, 0, 0, 0);
        }
#pragma unroll
        for (int j = 0; j < 4; ++j) {
            int node = wbase + T * 16 + lq * 4 + j;
            if (node < n) {
                if (l15 < 8) als[(size_t)node * 8 + l15] = acca[j];
                else         ald[(size_t)node * 8 + (l15 - 8)] = acca[j];
            }
        }
    }
}

// ---------------- Layer 1 aggregation (unroll 4, bf16x2 gathers) ----------------

__global__ __launch_bounds__(256) void k_agg1(const unsigned* __restrict__ hu,
                                              const float* __restrict__ als,
                                              const float* __restrict__ ald,
                                              const float* __restrict__ bias,
                                              const int* __restrict__ row_start,
                                              const int* __restrict__ csr_src,
                                              unsigned* __restrict__ out1u, int n) {
    int t = threadIdx.x;
    int l = t & 63;
    int nn = blockIdx.x * 4 + (t >> 6);
    if (nn >= n) return;
    int hd = l >> 3;
    int beg = row_start[nn], end = row_start[nn + 1];
    float aldv = ald[(size_t)nn * 8 + hd];
    float aX[4] = {0.f, 0.f, 0.f, 0.f}, aY[4] = {0.f, 0.f, 0.f, 0.f};
    float dn[4] = {0.f, 0.f, 0.f, 0.f};
    int i = beg;
    for (; i < end && (i & 3); ++i) {
        int s = csr_src[i];
        float e = als[(size_t)s * 8 + hd] + aldv;
        unsigned v = hu[(size_t)s * 64 + l];
        e = (e < 0.f) ? SLOPE * e : e;
        float xv = __expf(e);
        dn[0] += xv;
        aX[0] = fmaf(xv, __uint_as_float(v << 16), aX[0]);
        aY[0] = fmaf(xv, __uint_as_float(v & 0xFFFF0000u), aY[0]);
    }
    for (; i + 4 <= end; i += 4) {
        int4 s4 = *(const int4*)&csr_src[i];
        float e0 = als[(size_t)s4.x * 8 + hd];
        float e1 = als[(size_t)s4.y * 8 + hd];
        float e2 = als[(size_t)s4.z * 8 + hd];
        float e3 = als[(size_t)s4.w * 8 + hd];
        unsigned v0 = hu[(size_t)s4.x * 64 + l];
        unsigned v1 = hu[(size_t)s4.y * 64 + l];
        unsigned v2 = hu[(size_t)s4.z * 64 + l];
        unsigned v3 = hu[(size_t)s4.w * 64 + l];
        e0 += aldv; e0 = (e0 < 0.f) ? SLOPE * e0 : e0;
        e1 += aldv; e1 = (e1 < 0.f) ? SLOPE * e1 : e1;
        e2 += aldv; e2 = (e2 < 0.f) ? SLOPE * e2 : e2;
        e3 += aldv; e3 = (e3 < 0.f) ? SLOPE * e3 : e3;
        float x0 = __expf(e0), x1 = __expf(e1), x2 = __expf(e2), x3 = __expf(e3);
        dn[0] += x0; dn[1] += x1; dn[2] += x2; dn[3] += x3;
        aX[0] = fmaf(x0, __uint_as_float(v0 << 16), aX[0]);
        aY[0] = fmaf(x0, __uint_as_float(v0 & 0xFFFF0000u), aY[0]);
        aX[1] = fmaf(x1, __uint_as_float(v1 << 16), aX[1]);
        aY[1] = fmaf(x1, __uint_as_float(v1 & 0xFFFF0000u), aY[1]);
        aX[2] = fmaf(x2, __uint_as_float(v2 << 16), aX[2]);
        aY[2] = fmaf(x2, __uint_as_float(v2 & 0xFFFF0000u), aY[2]);
        aX[3] = fmaf(x3, __uint_as_float(v3 << 16), aX[3]);
        aY[3] = fmaf(x3, __uint_as_float(v3 & 0xFFFF0000u), aY[3]);
    }
    for (; i < end; ++i) {
        int s = csr_src[i];
        float e = als[(size_t)s * 8 + hd] + aldv;
        unsigned v = hu[(size_t)s * 64 + l];
        e = (e < 0.f) ? SLOPE * e : e;
        float xv = __expf(e);
        dn[0] += xv;
        aX[0] = fmaf(xv, __uint_as_float(v << 16), aX[0]);
        aY[0] = fmaf(xv, __uint_as_float(v & 0xFFFF0000u), aY[0]);
    }
    float inv = 1.f / (dn[0] + dn[1] + dn[2] + dn[3]);
    float2 bv = *(const float2*)&bias[2 * l];
    float rx = fmaxf((aX[0] + aX[1] + aX[2] + aX[3]) * inv + bv.x, 0.f);
    float ry = fmaxf((aY[0] + aY[1] + aY[2] + aY[3]) * inv + bv.y, 0.f);
    out1u[(size_t)nn * 64 + l] = pack2bf16(rx, ry);
}

// ---------------- Layer 2 GEMM via MFMA ----------------

__global__ __launch_bounds__(256) void k_gemm2m(const unsigned short* __restrict__ o1,
                                                const unsigned short* __restrict__ W2t,
                                                const float* __restrict__ as2,
                                                const float* __restrict__ ad2,
                                                float* __restrict__ h2,
                                                float* __restrict__ als,
                                                float* __restrict__ ald, int n) {
    int tid = threadIdx.x;
    int w = tid >> 6, l = tid & 63;
    int l15 = l & 15, lq = l >> 4;
    int wbase = blockIdx.x * 128 + w * 32;
    f4v acc[2] = {};
    int r0 = min(wbase + l15, n - 1);
    int r1 = min(wbase + 16 + l15, n - 1);
#pragma unroll
    for (int kb = 0; kb < 4; ++kb) {
        int ko = kb * 32 + lq * 8;
        s8v a0 = *(const s8v*)&o1[(size_t)r0 * 128 + ko];
        s8v a1 = *(const s8v*)&o1[(size_t)r1 * 128 + ko];
        s8v b  = *(const s8v*)&W2t[(size_t)l15 * 128 + ko];
        acc[0] = __builtin_amdgcn_mfma_f32_16x16x32_bf16(a0, b, acc[0], 0, 0, 0);
        acc[1] = __builtin_amdgcn_mfma_f32_16x16x32_bf16(a1, b, acc[1], 0, 0, 0);
    }
    float asv = as2[l15], adv = ad2[l15];
#pragma unroll
    for (int T = 0; T < 2; ++T) {
#pragma unroll
        for (int j = 0; j < 4; ++j) {
            int node = wbase + T * 16 + lq * 4 + j;
            float hv = acc[T][j];
            float ps = hv * asv, pd = hv * adv;
            ps += __shfl_xor(ps, 1); ps += __shfl_xor(ps, 2);
            ps += __shfl_xor(ps, 4); ps += __shfl_xor(ps, 8);
            pd += __shfl_xor(pd, 1); pd += __shfl_xor(pd, 2);
            pd += __shfl_xor(pd, 4); pd += __shfl_xor(pd, 8);
            if (node < n) {
                h2[(size_t)node * 16 + l15] = hv;
                if (l15 == 0) { als[node] = ps; ald[node] = pd; }
            }
        }
    }
}

// ---------------- Layer 2 aggregation (unroll 4) ----------------

__global__ __launch_bounds__(256) void k_agg2(const float* __restrict__ h,
                                              const float* __restrict__ als,
                                              const float* __restrict__ ald,
                                              const float* __restrict__ bias,
                                              const int* __restrict__ row_start,
                                              const int* __restrict__ csr_src,
                                              float* __restrict__ out, int n) {
    int tid = threadIdx.x;
    int nn = blockIdx.x * 16 + (tid >> 4);
    int c = tid & 15;
    if (nn >= n) return;
    int beg = row_start[nn], end = row_start[nn + 1];
    float aldv = ald[nn];
    float ac[4] = {0.f, 0.f, 0.f, 0.f}, dn[4] = {0.f, 0.f, 0.f, 0.f};
    int i = beg;
    for (; i < end && (i & 3); ++i) {
        int s = csr_src[i];
        float e = als[s] + aldv;
        e = (e < 0.f) ? SLOPE * e : e;
        float xv = __expf(e);
        dn[0] += xv;
        ac[0] = fmaf(xv, h[(size_t)s * 16 + c], ac[0]);
    }
    for (; i + 4 <= end; i += 4) {
        int4 s4 = *(const int4*)&csr_src[i];
        float e0 = als[s4.x], e1 = als[s4.y], e2 = als[s4.z], e3 = als[s4.w];
        float v0 = h[(size_t)s4.x * 16 + c];
        float v1 = h[(size_t)s4.y * 16 + c];
        float v2 = h[(size_t)s4.z * 16 + c];
        float v3 = h[(size_t)s4.w * 16 + c];
        e0 += aldv; e0 = (e0 < 0.f) ? SLOPE * e0 : e0;
        e1 += aldv; e1 = (e1 < 0.f) ? SLOPE * e1 : e1;
        e2 += aldv; e2 = (e2 < 0.f) ? SLOPE * e2 : e2;
        e3 += aldv; e3 = (e3 < 0.f) ? SLOPE * e3 : e3;
        float x0 = __expf(e0), x1 = __expf(e1), x2 = __expf(e2), x3 = __expf(e3);
        dn[0] += x0; dn[1] += x1; dn[2] += x2; dn[3] += x3;
        ac[0] = fmaf(x0, v0, ac[0]);
        ac[1] = fmaf(x1, v1, ac[1]);
        ac[2] = fmaf(x2, v2, ac[2]);
        ac[3] = fmaf(x3, v3, ac[3]);
    }
    for (; i < end; ++i) {
        int s = csr_src[i];
        float e = als[s] + aldv;
        e = (e < 0.f) ? SLOPE * e : e;
        float xv = __expf(e);
        dn[0] += xv;
        ac[0] = fmaf(xv, h[(size_t)s * 16 + c], ac[0]);
    }
    out[(size_t)nn * 16 + c] =
        fmaxf((ac[0] + ac[1] + ac[2] + ac[3]) / (dn[0] + dn[1] + dn[2] + dn[3]) + bias[c], 0.f);
}

// ---------------- launch ----------------

extern "C" void kernel_launch(void* const* d_in, const int* in_sizes, int n_in,
                              void* d_out, int out_size, void* d_ws, size_t ws_size,
                              hipStream_t stream) {
    const float* x   = (const float*)d_in[0];
    const int*   ei  = (const int*)d_in[1];
    const float* W1  = (const float*)d_in[2];
    const float* as1 = (const float*)d_in[3];
    const float* ad1 = (const float*)d_in[4];
    const float* b1  = (const float*)d_in[5];
    const float* W2  = (const float*)d_in[6];
    const float* as2 = (const float*)d_in[7];
    const float* ad2 = (const float*)d_in[8];
    const float* b2  = (const float*)d_in[9];

    int N = in_sizes[0] / NFEAT;
    int E = in_sizes[1] / 2;
    const int* srcp = ei;
    const int* dstp = ei + E;
    int NBUCK = (N + 255) >> BSH;

    char* ws = (char*)d_ws;
    size_t off = 0;
    auto take = [&](size_t bytes) -> char* {
        char* p = ws + off;
        off = (off + bytes + 255) & ~(size_t)255;
        return p;
    };
    int*            row_start = (int*)take((size_t)(N + 1) * 4);
    int*            bcount    = (int*)take(256 * 4);
    int*            pstart    = (int*)take(256 * 4);
    int*            pcursor   = (int*)take(256 * 4);
    uint2*          pairs     = (uint2*)take((size_t)E * 8);
    int*            csr       = (int*)take((size_t)(E + N) * 4);
    unsigned*       Wt1       = (unsigned*)take((size_t)128 * 64 * 4);
    unsigned short* Aat1      = (unsigned short*)take((size_t)16 * 128 * 2);
    unsigned*       W2t       = (unsigned*)take((size_t)16 * 64 * 4);
    unsigned*       h1u       = (unsigned*)take((size_t)N * 64 * 4);   // bf16x2
    float*          als1      = (float*)take((size_t)N * 8 * 4);
    float*          ald1      = (float*)take((size_t)N * 8 * 4);
    unsigned*       out1u     = (unsigned*)take((size_t)N * 64 * 4);   // bf16x2
    float*          h2        = (float*)take((size_t)N * 16 * 4);
    float*          als2      = (float*)take((size_t)N * 4);
    float*          ald2      = (float*)take((size_t)N * 4);

    // CSR build (bucketed counting sort; no global 4B-scatter, no long scan chain)
    k_zero<<<1, 256, 0, stream>>>(bcount, 256);
    k_bhist<<<256, 256, 0, stream>>>(dstp, E, bcount);
    k_bscan<<<1, 256, 0, stream>>>(bcount, pstart, pcursor, row_start, E, N);
    int chunk = (E + 127) / 128;
    k_bscatter<<<128, 256, 0, stream>>>(srcp, dstp, E, chunk, pcursor, pairs);
    k_bucket_csr<<<NBUCK, 256, 0, stream>>>(pairs, pstart, bcount, row_start, csr, N);

    // layers
    k_prep<<<44, 256, 0, stream>>>(W1, as1, ad1, W2, Wt1, Aat1, W2t);
    k_gemm1m<<<(N + 127) / 128, 256, 0, stream>>>(x, (const unsigned short*)Wt1, Aat1,
                                                  h1u, als1, ald1, N);
    k_agg1<<<(N + 3) / 4, 256, 0, stream>>>(h1u, als1, ald1, b1, row_start, csr, out1u, N);
    k_gemm2m<<<(N + 127) / 128, 256, 0, stream>>>((const unsigned short*)out1u,
                                                  (const unsigned short*)W2t,
                                                  as2, ad2, h2, als2, ald2, N);
    k_agg2<<<(N + 15) / 16, 256, 0, stream>>>(h2, als2, ald2, b2, row_start, csr, (float*)d_out, N);
}

// Round 7
// 145.724 us; speedup vs baseline: 2.8400x; 1.0445x over previous
//
#include <hip/hip_runtime.h>

#define NFEAT 128
#define HEADS 8
#define NHID 16
#define SLOPE 0.2f
#define BSH 8            // 256 dst nodes per bucket; NBUCK = ceil(N/256) <= 256 (N <= 65536)

typedef short s8v __attribute__((ext_vector_type(8)));   // 8 bf16 (4 VGPRs) MFMA A/B frag
typedef float f4v __attribute__((ext_vector_type(4)));   // 4 f32 MFMA C/D frag

// bf16 round-to-nearest-even pack helpers
__device__ __forceinline__ unsigned bf16rne(float f) {
    unsigned u = __float_as_uint(f);
    return (u + 0x7FFFu + ((u >> 16) & 1u)) >> 16;
}
__device__ __forceinline__ unsigned pack2bf16(float a, float b) {
    return bf16rne(a) | (bf16rne(b) << 16);
}
__device__ __forceinline__ float bflo(unsigned w) { return __uint_as_float(w << 16); }
__device__ __forceinline__ float bfhi(unsigned w) { return __uint_as_float(w & 0xFFFF0000u); }
// build an 8-element bf16 A/B fragment from 8 consecutive f32
__device__ __forceinline__ s8v frag_from_f32(const float* p) {
    float4 q0 = *(const float4*)p;
    float4 q1 = *(const float4*)(p + 4);
    union { s8v v; unsigned u[4]; } r;
    r.u[0] = pack2bf16(q0.x, q0.y); r.u[1] = pack2bf16(q0.z, q0.w);
    r.u[2] = pack2bf16(q1.x, q1.y); r.u[3] = pack2bf16(q1.z, q1.w);
    return r.v;
}

// ---------------- bucketed CSR build ----------------

__global__ void k_zero(int* __restrict__ p, int m) {
    int i = blockIdx.x * blockDim.x + threadIdx.x;
    if (i < m) p[i] = 0;
}

// coarse histogram of dst>>BSH (LDS-staged, one global atomic per bucket per block)
__global__ __launch_bounds__(256) void k_bhist(const int* __restrict__ dst, int E,
                                               int* __restrict__ bcount) {
    __shared__ int h[256];
    int t = threadIdx.x;
    h[t] = 0;
    __syncthreads();
    int stride = gridDim.x * 256;
    for (int i = blockIdx.x * 256 + t; i < E; i += stride)
        atomicAdd(&h[dst[i] >> BSH], 1);
    __syncthreads();
    int v = h[t];
    if (v) atomicAdd(&bcount[t], v);
}

// exclusive scan of bucket counts -> pair_start, pair_cursor; also row_start[n]
__global__ __launch_bounds__(256) void k_bscan(const int* __restrict__ bcount,
                                               int* __restrict__ pair_start,
                                               int* __restrict__ pair_cursor,
                                               int* __restrict__ row_start,
                                               int E, int n) {
    __shared__ int sh[256];
    int t = threadIdx.x;
    int nb = (n + 255) >> BSH;
    int v = (t < nb) ? bcount[t] : 0;
    sh[t] = v;
    __syncthreads();
    for (int off = 1; off < 256; off <<= 1) {
        int u = (t >= off) ? sh[t - off] : 0;
        __syncthreads();
        sh[t] += u;
        __syncthreads();
    }
    int excl = sh[t] - v;
    pair_start[t] = excl;
    pair_cursor[t] = excl;
    if (t == 0) row_start[n] = E + n;
}

// partition edges into bucket-contiguous (src,dst) pair segments
__global__ __launch_bounds__(256) void k_bscatter(const int* __restrict__ src,
                                                  const int* __restrict__ dst,
                                                  int E, int chunk,
                                                  int* __restrict__ pair_cursor,
                                                  uint2* __restrict__ pairs) {
    __shared__ int cnt[256], base[256];
    int t = threadIdx.x;
    int beg = blockIdx.x * chunk;
    int end = min(beg + chunk, E);
    if (beg >= end) return;
    cnt[t] = 0;
    __syncthreads();
    for (int i = beg + t; i < end; i += 256)
        atomicAdd(&cnt[dst[i] >> BSH], 1);
    __syncthreads();
    int c = cnt[t];
    base[t] = c ? atomicAdd(&pair_cursor[t], c) : 0;
    __syncthreads();
    cnt[t] = 0;
    __syncthreads();
    for (int i = beg + t; i < end; i += 256) {
        int d = dst[i];
        int b = d >> BSH;
        int ofs = atomicAdd(&cnt[b], 1);
        pairs[base[b] + ofs] = make_uint2((unsigned)src[i], (unsigned)d);
    }
}

// per-bucket: degree count (+1 self loop) -> row_start; scatter csr via LDS cursors
__global__ __launch_bounds__(256) void k_bucket_csr(const uint2* __restrict__ pairs,
                                                    const int* __restrict__ pair_start,
                                                    const int* __restrict__ bcount,
                                                    int* __restrict__ row_start,
                                                    int* __restrict__ csr, int n) {
    __shared__ int deg[256], sc[256];
    int b = blockIdx.x, t = threadIdx.x;
    int d0 = b << BSH;
    int nd = min(256, n - d0);
    deg[t] = (t < nd) ? 1 : 0;   // self loop
    __syncthreads();
    int pbeg = pair_start[b], pend = pbeg + bcount[b];
    for (int i = pbeg + t; i < pend; i += 256)
        atomicAdd(&deg[pairs[i].y - d0], 1);
    __syncthreads();
    int v = deg[t];
    sc[t] = v;
    __syncthreads();
    for (int off = 1; off < 256; off <<= 1) {
        int u = (t >= off) ? sc[t - off] : 0;
        __syncthreads();
        sc[t] += u;
        __syncthreads();
    }
    int excl = sc[t] - v;
    int cbase = pair_start[b] + d0;        // csr base of this bucket
    if (t < nd) row_start[d0 + t] = cbase + excl;
    __syncthreads();
    deg[t] = excl;                          // reuse as cursor
    __syncthreads();
    if (t < nd) {                           // self loop entry
        int pos = atomicAdd(&deg[t], 1);
        csr[cbase + pos] = d0 + t;
    }
    for (int i = pbeg + t; i < pend; i += 256) {
        uint2 p = pairs[i];
        int pos = atomicAdd(&deg[p.y - d0], 1);
        csr[cbase + pos] = (int)p.x;
    }
}

// ---------------- weight prep (parallel): Wt1[128c][128k], Aat1[16][128], W2t[16c][128k] ----------------

__global__ __launch_bounds__(256) void k_prep(const float* __restrict__ W1,
                                              const float* __restrict__ as1,
                                              const float* __restrict__ ad1,
                                              const float* __restrict__ W2,
                                              unsigned* __restrict__ Wt1,          // [128][64] u32
                                              unsigned short* __restrict__ Aat1,   // [16][128]
                                              unsigned* __restrict__ W2t) {        // [16][64] u32
    int t = blockIdx.x * 256 + threadIdx.x;
    if (t < 8192) {
        int c = t >> 6, m = t & 63;
        int k = 2 * m;
        Wt1[t] = pack2bf16(W1[k * 128 + c], W1[(k + 1) * 128 + c]);
    } else if (t < 10240) {
        int idx = t - 8192;
        int j = idx >> 7, k = idx & 127;
        float v = 0.f;
        if (j < 8)  { if ((k >> 4) == j)     v = as1[k]; }
        else        { if ((k >> 4) == j - 8) v = ad1[k]; }
        Aat1[idx] = (unsigned short)bf16rne(v);
    } else if (t < 11264) {
        int idx = t - 10240;
        int c = idx >> 6, m = idx & 63;
        int k = 2 * m;
        W2t[idx] = pack2bf16(W2[k * 16 + c], W2[(k + 1) * 16 + c]);
    }
}

// ---------------- Layer 1 GEMM via MFMA: h1(bf16) = x @ W1, logits via 2nd MFMA ----------------

__global__ __launch_bounds__(256) void k_gemm1m(const float* __restrict__ xf,
                                                const unsigned short* __restrict__ Wt,
                                                const unsigned short* __restrict__ Aat,
                                                unsigned* __restrict__ h1u,     // [n][64] bf16x2
                                                float* __restrict__ als,
                                                float* __restrict__ ald, int n) {
    __shared__ unsigned hl[4][32 * 64];   // per-wave h repack (swizzled), 32 KB
    int tid = threadIdx.x;
    int w = tid >> 6, l = tid & 63;
    int l15 = l & 15, lq = l >> 4;
    int wbase = blockIdx.x * 128 + w * 32;
    f4v acc[2][8] = {};
    int r0 = min(wbase + l15, n - 1);
    int r1 = min(wbase + 16 + l15, n - 1);
#pragma unroll
    for (int kb = 0; kb < 4; ++kb) {
        int ko = kb * 32 + lq * 8;
        s8v a0 = frag_from_f32(&xf[(size_t)r0 * 128 + ko]);
        s8v a1 = frag_from_f32(&xf[(size_t)r1 * 128 + ko]);
#pragma unroll
        for (int cg = 0; cg < 8; ++cg) {
            s8v b = *(const s8v*)&Wt[(size_t)(cg * 16 + l15) * 128 + ko];
            acc[0][cg] = __builtin_amdgcn_mfma_f32_16x16x32_bf16(a0, b, acc[0][cg], 0, 0, 0);
            acc[1][cg] = __builtin_amdgcn_mfma_f32_16x16x32_bf16(a1, b, acc[1][cg], 0, 0, 0);
        }
    }
    unsigned* myl = hl[w];
#pragma unroll
    for (int T = 0; T < 2; ++T) {
#pragma unroll
        for (int cg = 0; cg < 8; ++cg) {
#pragma unroll
            for (int j = 0; j < 4; ++j) {
                float v = acc[T][cg][j];
                float vo = __shfl_xor(v, 1);
                if ((l15 & 1) == 0) {
                    int nd = T * 16 + lq * 4 + j;
                    int wd = cg * 8 + (l15 >> 1);
                    int widx = nd * 64 + (((wd >> 2) ^ (nd & 15)) << 2) + (wd & 3);
                    myl[widx] = pack2bf16(v, vo);
                }
            }
        }
    }
    __syncthreads();
#pragma unroll
    for (int it = 0; it < 8; ++it) {
        int nd = it * 4 + lq;
        int node = wbase + nd;
        uint4 vv = *(const uint4*)&myl[nd * 64 + ((l15 ^ (nd & 15)) << 2)];
        if (node < n) *(uint4*)&h1u[(size_t)node * 64 + l15 * 4] = vv;
    }
#pragma unroll
    for (int T = 0; T < 2; ++T) {
        f4v acca = {};
#pragma unroll
        for (int kb = 0; kb < 4; ++kb) {
            int nd = T * 16 + l15;
            s8v ah = *(const s8v*)&myl[nd * 64 + (((kb * 4 + lq) ^ (nd & 15)) << 2)];
            s8v bb = *(const s8v*)&Aat[l15 * 128 + kb * 32 + lq * 8];
            acca = __builtin_amdgcn_mfma_f32_16x16x32_bf16(ah, bb, acca, 0, 0, 0);
        }
#pragma unroll
        for (int j = 0; j < 4; ++j) {
            int node = wbase + T * 16 + lq * 4 + j;
            if (node < n) {
                if (l15 < 8) als[(size_t)node * 8 + l15] = acca[j];
                else         ald[(size_t)node * 8 + (l15 - 8)] = acca[j];
            }
        }
    }
}

// ---------------- Layer 1 aggregation ----------------
// 1 wave per node; 4 edge-groups of 16 lanes; lane lc owns 8 channels (uint4 = 16B of the row).
// Register-only cross-group reduce via shfl_xor(16/32).

__global__ __launch_bounds__(256) void k_agg1(const unsigned* __restrict__ hu,
                                              const float* __restrict__ als,
                                              const float* __restrict__ ald,
                                              const float* __restrict__ bias,
                                              const int* __restrict__ row_start,
                                              const int* __restrict__ csr_src,
                                              unsigned* __restrict__ out1u, int n) {
    int t = threadIdx.x;
    int l = t & 63;
    int lc = l & 15, eg = l >> 4;
    int nn = blockIdx.x * 4 + (t >> 6);
    if (nn >= n) return;                   // whole wave exits together; no LDS/sync used
    int beg = row_start[nn], end = row_start[nn + 1];
    int len = end - beg;
    int g0 = beg + ((len * eg) >> 2);
    int g1 = beg + ((len * (eg + 1)) >> 2);
    int hd = lc >> 1;
    float aldv = ald[(size_t)nn * 8 + hd];
    float a[8] = {0.f, 0.f, 0.f, 0.f, 0.f, 0.f, 0.f, 0.f};
    float dn0 = 0.f, dn1 = 0.f;
    int i = g0;
    for (; i + 2 <= g1; i += 2) {
        int s0 = csr_src[i];
        int s1 = csr_src[i + 1];
        float e0 = als[(size_t)s0 * 8 + hd];
        float e1 = als[(size_t)s1 * 8 + hd];
        uint4 v0 = *(const uint4*)&hu[(size_t)s0 * 64 + lc * 4];
        uint4 v1 = *(const uint4*)&hu[(size_t)s1 * 64 + lc * 4];
        e0 += aldv; e0 = (e0 < 0.f) ? SLOPE * e0 : e0;
        e1 += aldv; e1 = (e1 < 0.f) ? SLOPE * e1 : e1;
        float x0 = __expf(e0), x1 = __expf(e1);
        dn0 += x0; dn1 += x1;
        a[0] = fmaf(x0, bflo(v0.x), a[0]); a[1] = fmaf(x0, bfhi(v0.x), a[1]);
        a[2] = fmaf(x0, bflo(v0.y), a[2]); a[3] = fmaf(x0, bfhi(v0.y), a[3]);
        a[4] = fmaf(x0, bflo(v0.z), a[4]); a[5] = fmaf(x0, bfhi(v0.z), a[5]);
        a[6] = fmaf(x0, bflo(v0.w), a[6]); a[7] = fmaf(x0, bfhi(v0.w), a[7]);
        a[0] = fmaf(x1, bflo(v1.x), a[0]); a[1] = fmaf(x1, bfhi(v1.x), a[1]);
        a[2] = fmaf(x1, bflo(v1.y), a[2]); a[3] = fmaf(x1, bfhi(v1.y), a[3]);
        a[4] = fmaf(x1, bflo(v1.z), a[4]); a[5] = fmaf(x1, bfhi(v1.z), a[5]);
        a[6] = fmaf(x1, bflo(v1.w), a[6]); a[7] = fmaf(x1, bfhi(v1.w), a[7]);
    }
    if (i < g1) {
        int s0 = csr_src[i];
        float e0 = als[(size_t)s0 * 8 + hd] + aldv;
        uint4 v0 = *(const uint4*)&hu[(size_t)s0 * 64 + lc * 4];
        e0 = (e0 < 0.f) ? SLOPE * e0 : e0;
        float x0 = __expf(e0);
        dn0 += x0;
        a[0] = fmaf(x0, bflo(v0.x), a[0]); a[1] = fmaf(x0, bfhi(v0.x), a[1]);
        a[2] = fmaf(x0, bflo(v0.y), a[2]); a[3] = fmaf(x0, bfhi(v0.y), a[3]);
        a[4] = fmaf(x0, bflo(v0.z), a[4]); a[5] = fmaf(x0, bfhi(v0.z), a[5]);
        a[6] = fmaf(x0, bflo(v0.w), a[6]); a[7] = fmaf(x0, bfhi(v0.w), a[7]);
    }
    float dn = dn0 + dn1;
#pragma unroll
    for (int j = 0; j < 8; ++j) {
        a[j] += __shfl_xor(a[j], 16);
        a[j] += __shfl_xor(a[j], 32);
    }
    dn += __shfl_xor(dn, 16);
    dn += __shfl_xor(dn, 32);
    if (eg == 0) {
        float inv = 1.f / dn;
        float4 b0 = *(const float4*)&bias[lc * 8];
        float4 b1 = *(const float4*)&bias[lc * 8 + 4];
        uint4 o;
        o.x = pack2bf16(fmaxf(a[0] * inv + b0.x, 0.f), fmaxf(a[1] * inv + b0.y, 0.f));
        o.y = pack2bf16(fmaxf(a[2] * inv + b0.z, 0.f), fmaxf(a[3] * inv + b0.w, 0.f));
        o.z = pack2bf16(fmaxf(a[4] * inv + b1.x, 0.f), fmaxf(a[5] * inv + b1.y, 0.f));
        o.w = pack2bf16(fmaxf(a[6] * inv + b1.z, 0.f), fmaxf(a[7] * inv + b1.w, 0.f));
        *(uint4*)&out1u[(size_t)nn * 64 + lc * 4] = o;
    }
}

// ---------------- Layer 2 GEMM via MFMA ----------------

__global__ __launch_bounds__(256) void k_gemm2m(const unsigned short* __restrict__ o1,
                                                const unsigned short* __restrict__ W2t,
                                                const float* __restrict__ as2,
                                                const float* __restrict__ ad2,
                                                float* __restrict__ h2,
                                                float* __restrict__ als,
                                                float* __restrict__ ald, int n) {
    int tid = threadIdx.x;
    int w = tid >> 6, l = tid & 63;
    int l15 = l & 15, lq = l >> 4;
    int wbase = blockIdx.x * 128 + w * 32;
    f4v acc[2] = {};
    int r0 = min(wbase + l15, n - 1);
    int r1 = min(wbase + 16 + l15, n - 1);
#pragma unroll
    for (int kb = 0; kb < 4; ++kb) {
        int ko = kb * 32 + lq * 8;
        s8v a0 = *(const s8v*)&o1[(size_t)r0 * 128 + ko];
        s8v a1 = *(const s8v*)&o1[(size_t)r1 * 128 + ko];
        s8v b  = *(const s8v*)&W2t[(size_t)l15 * 128 + ko];
        acc[0] = __builtin_amdgcn_mfma_f32_16x16x32_bf16(a0, b, acc[0], 0, 0, 0);
        acc[1] = __builtin_amdgcn_mfma_f32_16x16x32_bf16(a1, b, acc[1], 0, 0, 0);
    }
    float asv = as2[l15], adv = ad2[l15];
#pragma unroll
    for (int T = 0; T < 2; ++T) {
#pragma unroll
        for (int j = 0; j < 4; ++j) {
            int node = wbase + T * 16 + lq * 4 + j;
            float hv = acc[T][j];
            float ps = hv * asv, pd = hv * adv;
            ps += __shfl_xor(ps, 1); ps += __shfl_xor(ps, 2);
            ps += __shfl_xor(ps, 4); ps += __shfl_xor(ps, 8);
            pd += __shfl_xor(pd, 1); pd += __shfl_xor(pd, 2);
            pd += __shfl_xor(pd, 4); pd += __shfl_xor(pd, 8);
            if (node < n) {
                h2[(size_t)node * 16 + l15] = hv;
                if (l15 == 0) { als[node] = ps; ald[node] = pd; }
            }
        }
    }
}

// ---------------- Layer 2 aggregation ----------------
// 1 wave per node; 4 edge-groups of 16 lanes; lane lc owns 1 channel (4B of the 64B row).

__global__ __launch_bounds__(256) void k_agg2(const float* __restrict__ h,
                                              const float* __restrict__ als,
                                              const float* __restrict__ ald,
                                              const float* __restrict__ bias,
                                              const int* __restrict__ row_start,
                                              const int* __restrict__ csr_src,
                                              float* __restrict__ out, int n) {
    int t = threadIdx.x;
    int l = t & 63;
    int lc = l & 15, eg = l >> 4;
    int nn = blockIdx.x * 4 + (t >> 6);
    if (nn >= n) return;
    int beg = row_start[nn], end = row_start[nn + 1];
    int len = end - beg;
    int g0 = beg + ((len * eg) >> 2);
    int g1 = beg + ((len * (eg + 1)) >> 2);
    float aldv = ald[nn];
    float ac0 = 0.f, ac1 = 0.f, dn0 = 0.f, dn1 = 0.f;
    int i = g0;
    for (; i + 2 <= g1; i += 2) {
        int s0 = csr_src[i], s1 = csr_src[i + 1];
        float e0 = als[s0], e1 = als[s1];
        float v0 = h[(size_t)s0 * 16 + lc];
        float v1 = h[(size_t)s1 * 16 + lc];
        e0 += aldv; e0 = (e0 < 0.f) ? SLOPE * e0 : e0;
        e1 += aldv; e1 = (e1 < 0.f) ? SLOPE * e1 : e1;
        float x0 = __expf(e0), x1 = __expf(e1);
        dn0 += x0; dn1 += x1;
        ac0 = fmaf(x0, v0, ac0);
        ac1 = fmaf(x1, v1, ac1);
    }
    if (i < g1) {
        int s0 = csr_src[i];
        float e0 = als[s0] + aldv;
        e0 = (e0 < 0.f) ? SLOPE * e0 : e0;
        float x0 = __expf(e0);
        dn0 += x0;
        ac0 = fmaf(x0, h[(size_t)s0 * 16 + lc], ac0);
    }
    float ac = ac0 + ac1, dn = dn0 + dn1;
    ac += __shfl_xor(ac, 16); ac += __shfl_xor(ac, 32);
    dn += __shfl_xor(dn, 16); dn += __shfl_xor(dn, 32);
    if (eg == 0) out[(size_t)nn * 16 + lc] = fmaxf(ac / dn + bias[lc], 0.f);
}

// ---------------- launch ----------------

extern "C" void kernel_launch(void* const* d_in, const int* in_sizes, int n_in,
                              void* d_out, int out_size, void* d_ws, size_t ws_size,
                              hipStream_t stream) {
    const float* x   = (const float*)d_in[0];
    const int*   ei  = (const int*)d_in[1];
    const float* W1  = (const float*)d_in[2];
    const float* as1 = (const float*)d_in[3];
    const float* ad1 = (const float*)d_in[4];
    const float* b1  = (const float*)d_in[5];
    const float* W2  = (const float*)d_in[6];
    const float* as2 = (const float*)d_in[7];
    const float* ad2 = (const float*)d_in[8];
    const float* b2  = (const float*)d_in[9];

    int N = in_sizes[0] / NFEAT;
    int E = in_sizes[1] / 2;
    const int* srcp = ei;
    const int* dstp = ei + E;
    int NBUCK = (N + 255) >> BSH;

    char* ws = (char*)d_ws;
    size_t off = 0;
    auto take = [&](size_t bytes) -> char* {
        char* p = ws + off;
        off = (off + bytes + 255) & ~(size_t)255;
        return p;
    };
    int*            row_start = (int*)take((size_t)(N + 1) * 4);
    int*            bcount    = (int*)take(256 * 4);
    int*            pstart    = (int*)take(256 * 4);
    int*            pcursor   = (int*)take(256 * 4);
    uint2*          pairs     = (uint2*)take((size_t)E * 8);
    int*            csr       = (int*)take((size_t)(E + N) * 4);
    unsigned*       Wt1       = (unsigned*)take((size_t)128 * 64 * 4);
    unsigned short* Aat1      = (unsigned short*)take((size_t)16 * 128 * 2);
    unsigned*       W2t       = (unsigned*)take((size_t)16 * 64 * 4);
    unsigned*       h1u       = (unsigned*)take((size_t)N * 64 * 4);   // bf16x2
    float*          als1      = (float*)take((size_t)N * 8 * 4);
    float*          ald1      = (float*)take((size_t)N * 8 * 4);
    unsigned*       out1u     = (unsigned*)take((size_t)N * 64 * 4);   // bf16x2
    float*          h2        = (float*)take((size_t)N * 16 * 4);
    float*          als2      = (float*)take((size_t)N * 4);
    float*          ald2      = (float*)take((size_t)N * 4);

    // CSR build (bucketed counting sort)
    k_zero<<<1, 256, 0, stream>>>(bcount, 256);
    k_bhist<<<256, 256, 0, stream>>>(dstp, E, bcount);
    k_bscan<<<1, 256, 0, stream>>>(bcount, pstart, pcursor, row_start, E, N);
    int chunk = (E + 127) / 128;
    k_bscatter<<<128, 256, 0, stream>>>(srcp, dstp, E, chunk, pcursor, pairs);
    k_bucket_csr<<<NBUCK, 256, 0, stream>>>(pairs, pstart, bcount, row_start, csr, N);

    // layers
    k_prep<<<44, 256, 0, stream>>>(W1, as1, ad1, W2, Wt1, Aat1, W2t);
    k_gemm1m<<<(N + 127) / 128, 256, 0, stream>>>(x, (const unsigned short*)Wt1, Aat1,
                                                  h1u, als1, ald1, N);
    k_agg1<<<(N + 3) / 4, 256, 0, stream>>>(h1u, als1, ald1, b1, row_start, csr, out1u, N);
    k_gemm2m<<<(N + 127) / 128, 256, 0, stream>>>((const unsigned short*)out1u,
                                                  (const unsigned short*)W2t,
                                                  as2, ad2, h2, als2, ald2, N);
    k_agg2<<<(N + 3) / 4, 256, 0, stream>>>(h2, als2, ald2, b2, row_start, csr, (float*)d_out, N);
}

// Round 9
// 142.793 us; speedup vs baseline: 2.8983x; 1.0205x over previous
//
#include <hip/hip_runtime.h>

#define NFEAT 128
#define HEADS 8
#define NHID 16
#define SLOPE 0.2f
#define BSH 8            // 256 dst nodes per bucket; NBUCK = ceil(N/256) <= 256 (N <= 65536)

typedef __fp16 f16x8 __attribute__((ext_vector_type(8)));   // MFMA A/B frag (4 VGPRs)
typedef __fp16 f16x2 __attribute__((ext_vector_type(2)));
typedef float  f4v   __attribute__((ext_vector_type(4)));   // MFMA C/D frag

__device__ __forceinline__ unsigned pack2h(float a, float b) {
    union { f16x2 h; unsigned u; } r;
    r.h = __builtin_amdgcn_cvt_pkrtz(a, b);
    return r.u;
}
__device__ __forceinline__ f16x2 as_f16x2(unsigned u) {
    union { unsigned u; f16x2 h; } r; r.u = u; return r.h;
}
// build an 8-element fp16 A/B fragment from 8 consecutive f32
__device__ __forceinline__ f16x8 frag_from_f32(const float* p) {
    float4 q0 = *(const float4*)p;
    float4 q1 = *(const float4*)(p + 4);
    union { f16x8 v; f16x2 h[4]; } r;
    r.h[0] = __builtin_amdgcn_cvt_pkrtz(q0.x, q0.y);
    r.h[1] = __builtin_amdgcn_cvt_pkrtz(q0.z, q0.w);
    r.h[2] = __builtin_amdgcn_cvt_pkrtz(q1.x, q1.y);
    r.h[3] = __builtin_amdgcn_cvt_pkrtz(q1.z, q1.w);
    return r.v;
}

// ---------------- bucketed CSR build ----------------

__global__ void k_zero(int* __restrict__ p, int m) {
    int i = blockIdx.x * blockDim.x + threadIdx.x;
    if (i < m) p[i] = 0;
}

__global__ __launch_bounds__(256) void k_bhist(const int* __restrict__ dst, int E,
                                               int* __restrict__ bcount) {
    __shared__ int h[256];
    int t = threadIdx.x;
    h[t] = 0;
    __syncthreads();
    int stride = gridDim.x * 256;
    for (int i = blockIdx.x * 256 + t; i < E; i += stride)
        atomicAdd(&h[dst[i] >> BSH], 1);
    __syncthreads();
    int v = h[t];
    if (v) atomicAdd(&bcount[t], v);
}

__global__ __launch_bounds__(256) void k_bscan(const int* __restrict__ bcount,
                                               int* __restrict__ pair_start,
                                               int* __restrict__ pair_cursor,
                                               int* __restrict__ row_start,
                                               int E, int n) {
    __shared__ int sh[256];
    int t = threadIdx.x;
    int nb = (n + 255) >> BSH;
    int v = (t < nb) ? bcount[t] : 0;
    sh[t] = v;
    __syncthreads();
    for (int off = 1; off < 256; off <<= 1) {
        int u = (t >= off) ? sh[t - off] : 0;
        __syncthreads();
        sh[t] += u;
        __syncthreads();
    }
    int excl = sh[t] - v;
    pair_start[t] = excl;
    pair_cursor[t] = excl;
    if (t == 0) row_start[n] = E + n;
}

__global__ __launch_bounds__(256) void k_bscatter(const int* __restrict__ src,
                                                  const int* __restrict__ dst,
                                                  int E, int chunk,
                                                  int* __restrict__ pair_cursor,
                                                  uint2* __restrict__ pairs) {
    __shared__ int cnt[256], base[256];
    int t = threadIdx.x;
    int beg = blockIdx.x * chunk;
    int end = min(beg + chunk, E);
    if (beg >= end) return;
    cnt[t] = 0;
    __syncthreads();
    for (int i = beg + t; i < end; i += 256)
        atomicAdd(&cnt[dst[i] >> BSH], 1);
    __syncthreads();
    int c = cnt[t];
    base[t] = c ? atomicAdd(&pair_cursor[t], c) : 0;
    __syncthreads();
    cnt[t] = 0;
    __syncthreads();
    for (int i = beg + t; i < end; i += 256) {
        int d = dst[i];
        int b = d >> BSH;
        int ofs = atomicAdd(&cnt[b], 1);
        pairs[base[b] + ofs] = make_uint2((unsigned)src[i], (unsigned)d);
    }
}

__global__ __launch_bounds__(256) void k_bucket_csr(const uint2* __restrict__ pairs,
                                                    const int* __restrict__ pair_start,
                                                    const int* __restrict__ bcount,
                                                    int* __restrict__ row_start,
                                                    int* __restrict__ csr, int n) {
    __shared__ int deg[256], sc[256];
    int b = blockIdx.x, t = threadIdx.x;
    int d0 = b << BSH;
    int nd = min(256, n - d0);
    deg[t] = (t < nd) ? 1 : 0;   // self loop
    __syncthreads();
    int pbeg = pair_start[b], pend = pbeg + bcount[b];
    for (int i = pbeg + t; i < pend; i += 256)
        atomicAdd(&deg[pairs[i].y - d0], 1);
    __syncthreads();
    int v = deg[t];
    sc[t] = v;
    __syncthreads();
    for (int off = 1; off < 256; off <<= 1) {
        int u = (t >= off) ? sc[t - off] : 0;
        __syncthreads();
        sc[t] += u;
        __syncthreads();
    }
    int excl = sc[t] - v;
    int cbase = pair_start[b] + d0;        // csr base of this bucket
    if (t < nd) row_start[d0 + t] = cbase + excl;
    __syncthreads();
    deg[t] = excl;                          // reuse as cursor
    __syncthreads();
    if (t < nd) {                           // self loop entry
        int pos = atomicAdd(&deg[t], 1);
        csr[cbase + pos] = d0 + t;
    }
    for (int i = pbeg + t; i < pend; i += 256) {
        uint2 p = pairs[i];
        int pos = atomicAdd(&deg[p.y - d0], 1);
        csr[cbase + pos] = (int)p.x;
    }
}

// ---------------- weight prep: Wt1[128c][128k] f16, Aat1[16][128] f16, W2t[16c][128k] f16 ----------------

__global__ __launch_bounds__(256) void k_prep(const float* __restrict__ W1,
                                              const float* __restrict__ as1,
                                              const float* __restrict__ ad1,
                                              const float* __restrict__ W2,
                                              unsigned* __restrict__ Wt1,      // [128][64] u32 (f16x2)
                                              __fp16* __restrict__ Aat1,       // [16][128]
                                              unsigned* __restrict__ W2t) {    // [16][64] u32 (f16x2)
    int t = blockIdx.x * 256 + threadIdx.x;
    if (t < 8192) {
        int c = t >> 6, m = t & 63;
        int k = 2 * m;
        Wt1[t] = pack2h(W1[k * 128 + c], W1[(k + 1) * 128 + c]);
    } else if (t < 10240) {
        int idx = t - 8192;
        int j = idx >> 7, k = idx & 127;
        float v = 0.f;
        if (j < 8)  { if ((k >> 4) == j)     v = as1[k]; }
        else        { if ((k >> 4) == j - 8) v = ad1[k]; }
        Aat1[idx] = (__fp16)v;
    } else if (t < 11264) {
        int idx = t - 10240;
        int c = idx >> 6, m = idx & 63;
        int k = 2 * m;
        W2t[idx] = pack2h(W2[k * 16 + c], W2[(k + 1) * 16 + c]);
    }
}

// ---------------- Layer 1 GEMM via MFMA (f16): h1 = x @ W1, logits via 2nd MFMA ----------------

__global__ __launch_bounds__(256) void k_gemm1m(const float* __restrict__ xf,
                                                const __fp16* __restrict__ Wt,
                                                const __fp16* __restrict__ Aat,
                                                unsigned* __restrict__ h1u,     // [n][64] f16x2
                                                float* __restrict__ als,
                                                float* __restrict__ ald, int n) {
    __shared__ unsigned hl[4][32 * 64];   // per-wave h repack (swizzled), 32 KB
    int tid = threadIdx.x;
    int w = tid >> 6, l = tid & 63;
    int l15 = l & 15, lq = l >> 4;
    int wbase = blockIdx.x * 128 + w * 32;
    f4v acc[2][8] = {};
    int r0 = min(wbase + l15, n - 1);
    int r1 = min(wbase + 16 + l15, n - 1);
#pragma unroll
    for (int kb = 0; kb < 4; ++kb) {
        int ko = kb * 32 + lq * 8;
        f16x8 a0 = frag_from_f32(&xf[(size_t)r0 * 128 + ko]);
        f16x8 a1 = frag_from_f32(&xf[(size_t)r1 * 128 + ko]);
#pragma unroll
        for (int cg = 0; cg < 8; ++cg) {
            f16x8 b = *(const f16x8*)&Wt[(size_t)(cg * 16 + l15) * 128 + ko];
            acc[0][cg] = __builtin_amdgcn_mfma_f32_16x16x32_f16(a0, b, acc[0][cg], 0, 0, 0);
            acc[1][cg] = __builtin_amdgcn_mfma_f32_16x16x32_f16(a1, b, acc[1][cg], 0, 0, 0);
        }
    }
    unsigned* myl = hl[w];
#pragma unroll
    for (int T = 0; T < 2; ++T) {
#pragma unroll
        for (int cg = 0; cg < 8; ++cg) {
#pragma unroll
            for (int j = 0; j < 4; ++j) {
                float v = acc[T][cg][j];
                float vo = __shfl_xor(v, 1);
                if ((l15 & 1) == 0) {
                    int nd = T * 16 + lq * 4 + j;
                    int wd = cg * 8 + (l15 >> 1);
                    int widx = nd * 64 + (((wd >> 2) ^ (nd & 15)) << 2) + (wd & 3);
                    myl[widx] = pack2h(v, vo);
                }
            }
        }
    }
    __syncthreads();
#pragma unroll
    for (int it = 0; it < 8; ++it) {
        int nd = it * 4 + lq;
        int node = wbase + nd;
        uint4 vv = *(const uint4*)&myl[nd * 64 + ((l15 ^ (nd & 15)) << 2)];
        if (node < n) *(uint4*)&h1u[(size_t)node * 64 + l15 * 4] = vv;
    }
#pragma unroll
    for (int T = 0; T < 2; ++T) {
        f4v acca = {};
#pragma unroll
        for (int kb = 0; kb < 4; ++kb) {
            int nd = T * 16 + l15;
            f16x8 ah = *(const f16x8*)&myl[nd * 64 + (((kb * 4 + lq) ^ (nd & 15)) << 2)];
            f16x8 bb = *(const f16x8*)&Aat[l15 * 128 + kb * 32 + lq * 8];
            acca = __builtin_amdgcn_mfma_f32_16x16x32_f16(ah, bb, acca, 0, 0, 0);
        }
#pragma unroll
        for (int j = 0; j < 4; ++j) {
            int node = wbase + T * 16 + lq * 4 + j;
            if (node < n) {
                if (l15 < 8) als[(size_t)node * 8 + l15] = acca[j];
                else         ald[(size_t)node * 8 + (l15 - 8)] = acca[j];
            }
        }
    }
}

// ---------------- Layer 1 aggregation ----------------
// 1 wave per node; 4 edge-groups of 16 lanes; lane lc owns 8 channels (uint4 = 16B f16).
// Edge-pair inner loop: v_perm pairs channels across 2 edges, v_dot2_f32_f16 accumulates in f32.

__global__ __launch_bounds__(256) void k_agg1(const unsigned* __restrict__ hu,
                                              const float* __restrict__ als,
                                              const float* __restrict__ ald,
                                              const float* __restrict__ bias,
                                              const int* __restrict__ row_start,
                                              const int* __restrict__ csr_src,
                                              unsigned* __restrict__ out1u, int n) {
    int t = threadIdx.x;
    int l = t & 63;
    int lc = l & 15, eg = l >> 4;
    int nn = blockIdx.x * 4 + (t >> 6);
    if (nn >= n) return;                   // whole wave exits together; no LDS/sync used
    int beg = row_start[nn], end = row_start[nn + 1];
    int len = end - beg;
    int g0 = beg + ((len * eg) >> 2);
    int g1 = beg + ((len * (eg + 1)) >> 2);
    int hd = lc >> 1;
    float aldv = ald[(size_t)nn * 8 + hd];
    float a[8] = {0.f, 0.f, 0.f, 0.f, 0.f, 0.f, 0.f, 0.f};
    float dn = 0.f;
    f16x2 one2; one2[0] = (__fp16)1.f; one2[1] = (__fp16)1.f;
    int i = g0;
    for (; i + 2 <= g1; i += 2) {
        int s0 = csr_src[i];
        int s1 = csr_src[i + 1];
        float e0 = als[(size_t)s0 * 8 + hd];
        float e1 = als[(size_t)s1 * 8 + hd];
        uint4 v0 = *(const uint4*)&hu[(size_t)s0 * 64 + lc * 4];
        uint4 v1 = *(const uint4*)&hu[(size_t)s1 * 64 + lc * 4];
        e0 += aldv; e0 = (e0 < 0.f) ? SLOPE * e0 : e0;
        e1 += aldv; e1 = (e1 < 0.f) ? SLOPE * e1 : e1;
        f16x2 xx = __builtin_amdgcn_cvt_pkrtz(__expf(e0), __expf(e1));
        dn = __builtin_amdgcn_fdot2(xx, one2, dn, false);
        unsigned V0[4] = {v0.x, v0.y, v0.z, v0.w};
        unsigned V1[4] = {v1.x, v1.y, v1.z, v1.w};
#pragma unroll
        for (int j = 0; j < 4; ++j) {
            unsigned lo = __builtin_amdgcn_perm(V1[j], V0[j], 0x05040100u);
            unsigned hi = __builtin_amdgcn_perm(V1[j], V0[j], 0x07060302u);
            a[2 * j]     = __builtin_amdgcn_fdot2(xx, as_f16x2(lo), a[2 * j], false);
            a[2 * j + 1] = __builtin_amdgcn_fdot2(xx, as_f16x2(hi), a[2 * j + 1], false);
        }
    }
    if (i < g1) {
        int s0 = csr_src[i];
        float e0 = als[(size_t)s0 * 8 + hd] + aldv;
        uint4 v0 = *(const uint4*)&hu[(size_t)s0 * 64 + lc * 4];
        e0 = (e0 < 0.f) ? SLOPE * e0 : e0;
        float x0 = __expf(e0);
        dn += x0;
        unsigned V0[4] = {v0.x, v0.y, v0.z, v0.w};
#pragma unroll
        for (int j = 0; j < 4; ++j) {
            f16x2 p = as_f16x2(V0[j]);
            a[2 * j]     = fmaf(x0, (float)p[0], a[2 * j]);
            a[2 * j + 1] = fmaf(x0, (float)p[1], a[2 * j + 1]);
        }
    }
#pragma unroll
    for (int j = 0; j < 8; ++j) {
        a[j] += __shfl_xor(a[j], 16);
        a[j] += __shfl_xor(a[j], 32);
    }
    dn += __shfl_xor(dn, 16);
    dn += __shfl_xor(dn, 32);
    if (eg == 0) {
        float inv = 1.f / dn;
        float4 b0 = *(const float4*)&bias[lc * 8];
        float4 b1 = *(const float4*)&bias[lc * 8 + 4];
        uint4 o;
        o.x = pack2h(fmaxf(a[0] * inv + b0.x, 0.f), fmaxf(a[1] * inv + b0.y, 0.f));
        o.y = pack2h(fmaxf(a[2] * inv + b0.z, 0.f), fmaxf(a[3] * inv + b0.w, 0.f));
        o.z = pack2h(fmaxf(a[4] * inv + b1.x, 0.f), fmaxf(a[5] * inv + b1.y, 0.f));
        o.w = pack2h(fmaxf(a[6] * inv + b1.z, 0.f), fmaxf(a[7] * inv + b1.w, 0.f));
        *(uint4*)&out1u[(size_t)nn * 64 + lc * 4] = o;
    }
}

// ---------------- Layer 2 GEMM via MFMA (f16) ----------------

__global__ __launch_bounds__(256) void k_gemm2m(const __fp16* __restrict__ o1,
                                                const __fp16* __restrict__ W2t,
                                                const float* __restrict__ as2,
                                                const float* __restrict__ ad2,
                                                __fp16* __restrict__ h2,
                                                float* __restrict__ als,
                                                float* __restrict__ ald, int n) {
    int tid = threadIdx.x;
    int w = tid >> 6, l = tid & 63;
    int l15 = l & 15, lq = l >> 4;
    int wbase = blockIdx.x * 128 + w * 32;
    f4v acc[2] = {};
    int r0 = min(wbase + l15, n - 1);
    int r1 = min(wbase + 16 + l15, n - 1);
#pragma unroll
    for (int kb = 0; kb < 4; ++kb) {
        int ko = kb * 32 + lq * 8;
        f16x8 a0 = *(const f16x8*)&o1[(size_t)r0 * 128 + ko];
        f16x8 a1 = *(const f16x8*)&o1[(size_t)r1 * 128 + ko];
        f16x8 b  = *(const f16x8*)&W2t[(size_t)l15 * 128 + ko];
        acc[0] = __builtin_amdgcn_mfma_f32_16x16x32_f16(a0, b, acc[0], 0, 0, 0);
        acc[1] = __builtin_amdgcn_mfma_f32_16x16x32_f16(a1, b, acc[1], 0, 0, 0);
    }
    float asv = as2[l15], adv = ad2[l15];
#pragma unroll
    for (int T = 0; T < 2; ++T) {
#pragma unroll
        for (int j = 0; j < 4; ++j) {
            int node = wbase + T * 16 + lq * 4 + j;
            float hv = acc[T][j];
            float ps = hv * asv, pd = hv * adv;
            ps += __shfl_xor(ps, 1); ps += __shfl_xor(ps, 2);
            ps += __shfl_xor(ps, 4); ps += __shfl_xor(ps, 8);
            pd += __shfl_xor(pd, 1); pd += __shfl_xor(pd, 2);
            pd += __shfl_xor(pd, 4); pd += __shfl_xor(pd, 8);
            if (node < n) {
                h2[(size_t)node * 16 + l15] = (__fp16)hv;
                if (l15 == 0) { als[node] = ps; ald[node] = pd; }
            }
        }
    }
}

// ---------------- Layer 2 aggregation ----------------
// 1 wave per node; 4 edge-groups of 16 lanes; lane lc owns 1 channel (f16 2B of the 32B row).

__global__ __launch_bounds__(256) void k_agg2(const __fp16* __restrict__ h,
                                              const float* __restrict__ als,
                                              const float* __restrict__ ald,
                                              const float* __restrict__ bias,
                                              const int* __restrict__ row_start,
                                              const int* __restrict__ csr_src,
                                              float* __restrict__ out, int n) {
    int t = threadIdx.x;
    int l = t & 63;
    int lc = l & 15, eg = l >> 4;
    int nn = blockIdx.x * 4 + (t >> 6);
    if (nn >= n) return;
    int beg = row_start[nn], end = row_start[nn + 1];
    int len = end - beg;
    int g0 = beg + ((len * eg) >> 2);
    int g1 = beg + ((len * (eg + 1)) >> 2);
    float aldv = ald[nn];
    float ac0 = 0.f, ac1 = 0.f, dn0 = 0.f, dn1 = 0.f;
    int i = g0;
    for (; i + 2 <= g1; i += 2) {
        int s0 = csr_src[i], s1 = csr_src[i + 1];
        float e0 = als[s0], e1 = als[s1];
        float v0 = (float)h[(size_t)s0 * 16 + lc];
        float v1 = (float)h[(size_t)s1 * 16 + lc];
        e0 += aldv; e0 = (e0 < 0.f) ? SLOPE * e0 : e0;
        e1 += aldv; e1 = (e1 < 0.f) ? SLOPE * e1 : e1;
        float x0 = __expf(e0), x1 = __expf(e1);
        dn0 += x0; dn1 += x1;
        ac0 = fmaf(x0, v0, ac0);
        ac1 = fmaf(x1, v1, ac1);
    }
    if (i < g1) {
        int s0 = csr_src[i];
        float e0 = als[s0] + aldv;
        e0 = (e0 < 0.f) ? SLOPE * e0 : e0;
        float x0 = __expf(e0);
        dn0 += x0;
        ac0 = fmaf(x0, (float)h[(size_t)s0 * 16 + lc], ac0);
    }
    float ac = ac0 + ac1, dn = dn0 + dn1;
    ac += __shfl_xor(ac, 16); ac += __shfl_xor(ac, 32);
    dn += __shfl_xor(dn, 16); dn += __shfl_xor(dn, 32);
    if (eg == 0) out[(size_t)nn * 16 + lc] = fmaxf(ac / dn + bias[lc], 0.f);
}

// ---------------- launch ----------------

extern "C" void kernel_launch(void* const* d_in, const int* in_sizes, int n_in,
                              void* d_out, int out_size, void* d_ws, size_t ws_size,
                              hipStream_t stream) {
    const float* x   = (const float*)d_in[0];
    const int*   ei  = (const int*)d_in[1];
    const float* W1  = (const float*)d_in[2];
    const float* as1 = (const float*)d_in[3];
    const float* ad1 = (const float*)d_in[4];
    const float* b1  = (const float*)d_in[5];
    const float* W2  = (const float*)d_in[6];
    const float* as2 = (const float*)d_in[7];
    const float* ad2 = (const float*)d_in[8];
    const float* b2  = (const float*)d_in[9];

    int N = in_sizes[0] / NFEAT;
    int E = in_sizes[1] / 2;
    const int* srcp = ei;
    const int* dstp = ei + E;
    int NBUCK = (N + 255) >> BSH;

    char* ws = (char*)d_ws;
    size_t off = 0;
    auto take = [&](size_t bytes) -> char* {
        char* p = ws + off;
        off = (off + bytes + 255) & ~(size_t)255;
        return p;
    };
    int*       row_start = (int*)take((size_t)(N + 1) * 4);
    int*       bcount    = (int*)take(256 * 4);
    int*       pstart    = (int*)take(256 * 4);
    int*       pcursor   = (int*)take(256 * 4);
    uint2*     pairs     = (uint2*)take((size_t)E * 8);
    int*       csr       = (int*)take((size_t)(E + N) * 4);
    unsigned*  Wt1       = (unsigned*)take((size_t)128 * 64 * 4);
    __fp16*    Aat1      = (__fp16*)take((size_t)16 * 128 * 2);
    unsigned*  W2t       = (unsigned*)take((size_t)16 * 64 * 4);
    unsigned*  h1u       = (unsigned*)take((size_t)N * 64 * 4);   // f16x2
    float*     als1      = (float*)take((size_t)N * 8 * 4);
    float*     ald1      = (float*)take((size_t)N * 8 * 4);
    unsigned*  out1u     = (unsigned*)take((size_t)N * 64 * 4);   // f16x2
    __fp16*    h2        = (__fp16*)take((size_t)N * 16 * 2);
    float*     als2      = (float*)take((size_t)N * 4);
    float*     ald2      = (float*)take((size_t)N * 4);

    // CSR build (bucketed counting sort)
    k_zero<<<1, 256, 0, stream>>>(bcount, 256);
    k_bhist<<<256, 256, 0, stream>>>(dstp, E, bcount);
    k_bscan<<<1, 256, 0, stream>>>(bcount, pstart, pcursor, row_start, E, N);
    int chunk = (E + 127) / 128;
    k_bscatter<<<128, 256, 0, stream>>>(srcp, dstp, E, chunk, pcursor, pairs);
    k_bucket_csr<<<NBUCK, 256, 0, stream>>>(pairs, pstart, bcount, row_start, csr, N);

    // layers
    k_prep<<<44, 256, 0, stream>>>(W1, as1, ad1, W2, Wt1, Aat1, W2t);
    k_gemm1m<<<(N + 127) / 128, 256, 0, stream>>>(x, (const __fp16*)Wt1, Aat1,
                                                  h1u, als1, ald1, N);
    k_agg1<<<(N + 3) / 4, 256, 0, stream>>>(h1u, als1, ald1, b1, row_start, csr, out1u, N);
    k_gemm2m<<<(N + 127) / 128, 256, 0, stream>>>((const __fp16*)out1u,
                                                  (const __fp16*)W2t,
                                                  as2, ad2, h2, als2, ald2, N);
    k_agg2<<<(N + 3) / 4, 256, 0, stream>>>(h2, als2, ald2, b2, row_start, csr, (float*)d_out, N);
}